// Round 7
// baseline (336.278 us; speedup 1.0000x reference)
//
#include <hip/hip_runtime.h>
#include <hip/hip_bf16.h>
#include <math.h>

// ParallelMLayer: x_seq, v_seq = scan over A=sigmoid(F@WA.T+bA),
// dt=softplus(F@Wdt.T+bdt)*0.1*1.5^(d/128), B=(F@WB.T+bB)*dt
// v_t = A_t v_{t-1} + B_t ; x_t = x_{t-1} + dt_t * v_t
//
// R7: GEMM rebuilt as 256x256-tile, BK=32, 3-buffer counted-vmcnt pipeline
// (T3+T4): per K-tile `vmcnt(4)` (never 0) + raw s_barrier; prefetch of tile
// kt+2 issued inside the compute phases; setprio around MFMA (T5); XOR-swizzled
// gload_lds staging (conflict-free reads); XCD-aware block swizzle (T1).

#define BDIM 4
#define LSEQ 4096
#define DDIM 1024
#define MROWS (BDIM*LSEQ)   // 16384
#define NCH 128             // scan chunks per sequence
#define CLEN (LSEQ/NCH)     // 32
#define N4W (DDIM*DDIM/4)   // 262144 (2^18)
#define BK 32
#define KT (DDIM/BK)        // 32 K-tiles

typedef __attribute__((ext_vector_type(8))) short s16x8;
typedef __attribute__((ext_vector_type(4))) float f32x4;

__device__ inline ushort f2bf(float f) {
    unsigned u = __builtin_bit_cast(unsigned, f);
    unsigned r = (u + 0x7fffu + ((u >> 16) & 1u)) >> 16;
    return (ushort)r;
}

__device__ inline void gld_lds16(const ushort* g, ushort* l) {
    __builtin_amdgcn_global_load_lds(
        (const __attribute__((address_space(1))) void*)g,
        (__attribute__((address_space(3))) void*)l, 16, 0, 0);
}

// ---- f32 -> bf16 conversion, 4 elems/thread ----
__global__ void cvt4(const float* __restrict__ src, ushort* __restrict__ dst, int n4) {
    int i = blockIdx.x * 256 + threadIdx.x;
    if (i >= n4) return;
    float4 v = reinterpret_cast<const float4*>(src)[i];
    ushort4 o;
    o.x = f2bf(v.x); o.y = f2bf(v.y); o.z = f2bf(v.z); o.w = f2bf(v.w);
    reinterpret_cast<ushort4*>(dst)[i] = o;
}

// ---- three equal-size weight matrices -> one concatenated bf16 buffer ----
__global__ void cvt4_w3(const float* __restrict__ s0, const float* __restrict__ s1,
                        const float* __restrict__ s2, ushort* __restrict__ dst) {
    int i = blockIdx.x * 256 + threadIdx.x;      // 0 .. 3*N4W-1
    int w = i >> 18;                             // N4W = 2^18
    int j = i & (N4W - 1);
    const float* s = (w == 0) ? s0 : (w == 1) ? s1 : s2;
    float4 v = reinterpret_cast<const float4*>(s)[j];
    ushort4 o;
    o.x = f2bf(v.x); o.y = f2bf(v.y); o.z = f2bf(v.z); o.w = f2bf(v.w);
    reinterpret_cast<ushort4*>(dst)[i] = o;
}

// ---- fused GEMM: C[i][j] = sum_k F[i][k] * Wcat[j][k] ----
// 256x256 tile, BK=32, 512 threads (8 waves 2x4), per-wave 128x64 out.
// LDS: 3 buffers x (A 256x32 + B 256x32) bf16 = 96 KB.
// Swizzle: physical 16B-chunk p of row R holds global chunk p ^ ((R>>1)&3);
// same XOR on ds_read -> conflict-free (verified-0 pattern from R5).
__global__ __launch_bounds__(512) void gemm_fused(
    const ushort* __restrict__ F, const ushort* __restrict__ Wc,
    const float* __restrict__ biasA, const float* __restrict__ biasB,
    const float* __restrict__ biasDt,
    float* __restrict__ outA, float* __restrict__ outPre, float* __restrict__ outDt)
{
    __shared__ ushort As[3][256 * BK];   // 3 x 16 KB
    __shared__ ushort Bs[3][256 * BK];   // 3 x 16 KB
    const int t = threadIdx.x;
    // XCD-aware swizzle of the flat 768-block grid (768 % 8 == 0 -> bijective)
    const int swz = (blockIdx.x & 7) * 96 + (blockIdx.x >> 3);
    const int bi = swz / 12;     // 0..63  M tiles (XCD-contiguous: A-panel reuse)
    const int bj = swz % 12;     // 0..11  N tiles
    const int lane = t & 63, wid = t >> 6;
    const int wm = wid >> 2, wn = wid & 3;   // 2x4 waves, each 128x64 out
    const int lr = lane & 15, lg = lane >> 4;

    const size_t aBase = (size_t)bi * 256;
    const size_t bBase = (size_t)bj * 256;

    // staging: per gload instr, wave w covers rows h*128 + w*16 + (lane>>2),
    // physical chunk lane&3 holds global chunk (lane&3)^((lane>>3)&3)
    const int srow = wid * 16 + (lane >> 2);
    const int gchunk = (lane & 3) ^ ((lane >> 3) & 3);
    const ushort* gA[2]; const ushort* gB[2];
    int ldOff[2];
#pragma unroll
    for (int h = 0; h < 2; h++) {
        gA[h] = F  + (aBase + h * 128 + srow) * DDIM + gchunk * 8;
        gB[h] = Wc + (bBase + h * 128 + srow) * DDIM + gchunk * 8;
        ldOff[h] = (h * 128 + wid * 16) * BK;   // wave-uniform; HW adds lane*16B
    }

    f32x4 acc[8][4] = {};

    // prologue: stage tiles 0 -> buf0, 1 -> buf1 (8 loads outstanding)
#pragma unroll
    for (int kt = 0; kt < 2; kt++) {
#pragma unroll
        for (int h = 0; h < 2; h++) {
            gld_lds16(gA[h] + kt * BK, &As[kt][ldOff[h]]);
            gld_lds16(gB[h] + kt * BK, &Bs[kt][ldOff[h]]);
        }
    }

    int r = 0;                    // kt % 3
    for (int kt = 0; kt < KT; kt++) {
        // counted wait: tile kt's 4 loads retired; tile kt+1's 4 stay in flight
        asm volatile("s_waitcnt vmcnt(4)" ::: "memory");
        __builtin_amdgcn_s_barrier();
        const ushort* bufA = As[r];
        const ushort* bufB = Bs[r];
        int nr = r + 2; if (nr >= 3) nr -= 3;     // (kt+2) % 3
        const bool pf = (kt + 2) < KT;
        const int pfk = (kt + 2) * BK;

        // ---- phase A: prefetch A-halves of tile kt+2; B frags + A frags m0..3
        if (pf) {
            gld_lds16(gA[0] + pfk, &As[nr][ldOff[0]]);
            gld_lds16(gA[1] + pfk, &As[nr][ldOff[1]]);
        }
        s16x8 bfr[4], afr[4];
#pragma unroll
        for (int n = 0; n < 4; n++) {
            const int row = wn * 64 + n * 16 + lr;
            bfr[n] = *reinterpret_cast<const s16x8*>(
                &bufB[row * BK + ((lg ^ ((row >> 1) & 3)) * 8)]);
        }
#pragma unroll
        for (int m = 0; m < 4; m++) {
            const int row = wm * 128 + m * 16 + lr;
            afr[m] = *reinterpret_cast<const s16x8*>(
                &bufA[row * BK + ((lg ^ ((row >> 1) & 3)) * 8)]);
        }
        __builtin_amdgcn_s_setprio(1);
#pragma unroll
        for (int m = 0; m < 4; m++)
#pragma unroll
            for (int n = 0; n < 4; n++)
                acc[m][n] = __builtin_amdgcn_mfma_f32_16x16x32_bf16(afr[m], bfr[n], acc[m][n], 0, 0, 0);
        __builtin_amdgcn_s_setprio(0);

        // ---- phase B: prefetch B-halves of tile kt+2; A frags m4..7
        if (pf) {
            gld_lds16(gB[0] + pfk, &Bs[nr][ldOff[0]]);
            gld_lds16(gB[1] + pfk, &Bs[nr][ldOff[1]]);
        }
#pragma unroll
        for (int m = 0; m < 4; m++) {
            const int row = wm * 128 + (m + 4) * 16 + lr;
            afr[m] = *reinterpret_cast<const s16x8*>(
                &bufA[row * BK + ((lg ^ ((row >> 1) & 3)) * 8)]);
        }
        __builtin_amdgcn_s_setprio(1);
#pragma unroll
        for (int m = 0; m < 4; m++)
#pragma unroll
            for (int n = 0; n < 4; n++)
                acc[m + 4][n] = __builtin_amdgcn_mfma_f32_16x16x32_bf16(afr[m], bfr[n], acc[m + 4][n], 0, 0, 0);
        __builtin_amdgcn_s_setprio(0);

        r = r + 1; if (r >= 3) r -= 3;
    }

    // epilogue: C/D layout col=lane&15, row=(lane>>4)*4+reg
    const int mat = bj >> 2;                     // 0:A 1:B-pre 2:dt
    const int colBase = (bj & 3) * 256 + wn * 64;
    const size_t rowBase = (size_t)bi * 256 + wm * 128;

    if (mat == 0) {
#pragma unroll
        for (int n = 0; n < 4; n++) {
            const int d = colBase + n * 16 + lr;
            const float bb = biasA[d];
#pragma unroll
            for (int m = 0; m < 8; m++)
#pragma unroll
                for (int rix = 0; rix < 4; rix++) {
                    const size_t row = rowBase + m * 16 + lg * 4 + rix;
                    float s = acc[m][n][rix] + bb;
                    outA[row * DDIM + d] = 1.0f / (1.0f + expf(-s));
                }
        }
    } else if (mat == 1) {
#pragma unroll
        for (int n = 0; n < 4; n++) {
            const int d = colBase + n * 16 + lr;
            const float bb = biasB[d];
#pragma unroll
            for (int m = 0; m < 8; m++)
#pragma unroll
                for (int rix = 0; rix < 4; rix++) {
                    const size_t row = rowBase + m * 16 + lg * 4 + rix;
                    outPre[row * DDIM + d] = acc[m][n][rix] + bb;
                }
        }
    } else {
#pragma unroll
        for (int n = 0; n < 4; n++) {
            const int d = colBase + n * 16 + lr;
            const float bb = biasDt[d];
            const float scl = 0.1f * exp2f(0.58496250072f * (float)(d >> 7)); // 0.1*1.5^(d/128)
#pragma unroll
            for (int m = 0; m < 8; m++)
#pragma unroll
                for (int rix = 0; rix < 4; rix++) {
                    const size_t row = rowBase + m * 16 + lg * 4 + rix;
                    float s = acc[m][n][rix] + bb;
                    float sp = fmaxf(s, 0.0f) + log1pf(expf(-fabsf(s)));
                    outDt[row * DDIM + d] = sp * scl;
                }
        }
    }
}

// ---- scan pass 1: per (b, chunk, d) composite map (a, c, bv, bx), float4 ----
__global__ void scan_pass1(const float* __restrict__ A, const float* __restrict__ PRE,
                           const float* __restrict__ DT, float4* __restrict__ summ)
{
    const int c = blockIdx.x & (NCH - 1);
    const int b = blockIdx.x >> 7;       // NCH = 128
    const int d4 = threadIdx.x;          // 0..255, covers d = 4*d4..+3
    const f32x4* A4   = (const f32x4*)A;
    const f32x4* PRE4 = (const f32x4*)PRE;
    const f32x4* DT4  = (const f32x4*)DT;
    size_t idx = ((size_t)b * LSEQ + (size_t)c * CLEN) * (DDIM / 4) + d4;
    f32x4 a = {1.f,1.f,1.f,1.f}, cc = {}, bv = {}, bx = {};
    for (int i = 0; i < CLEN; i++) {
        f32x4 Av = A4[idx], pv = PRE4[idx], dtv = DT4[idx];
#pragma unroll
        for (int j = 0; j < 4; j++) {
            a[j] *= Av[j];
            cc[j] = fmaf(dtv[j], a[j], cc[j]);
            bv[j] = fmaf(Av[j], bv[j], pv[j] * dtv[j]);
            bx[j] = fmaf(dtv[j], bv[j], bx[j]);
        }
        idx += DDIM / 4;
    }
    const size_t base = ((size_t)b * NCH + c) * DDIM + (size_t)d4 * 4;
#pragma unroll
    for (int j = 0; j < 4; j++)
        summ[base + j] = make_float4(a[j], cc[j], bv[j], bx[j]);
}

// ---- scan pass 2: serial over chunks per channel -> carry-in (v, x) ----
__global__ void scan_pass2(const float4* __restrict__ summ, float2* __restrict__ carry)
{
    const int idx = blockIdx.x * 256 + threadIdx.x;   // 4096 channels
    const int b = idx >> 10, d = idx & 1023;
    float v = 0.0f, x = 0.0f;
    for (int c = 0; c < NCH; c++) {
        const size_t o = ((size_t)b * NCH + c) * DDIM + d;
        carry[o] = make_float2(v, x);
        float4 s = summ[o];
        x = x + s.y * v + s.w;   // x' = x + c*v + bx (uses OLD v)
        v = s.x * v + s.z;       // v' = a*v + bv
    }
}

// ---- scan pass 3: finalize with carry; in-place pre->v_seq, dt->x_seq ----
__global__ void scan_pass3(const float* __restrict__ A, float* __restrict__ PREV,
                           float* __restrict__ DTX, const float2* __restrict__ carry)
{
    const int c = blockIdx.x & (NCH - 1);
    const int b = blockIdx.x >> 7;
    const int d4 = threadIdx.x;
    const f32x4* A4 = (const f32x4*)A;
    f32x4* PREV4 = (f32x4*)PREV;
    f32x4* DTX4  = (f32x4*)DTX;
    size_t idx = ((size_t)b * LSEQ + (size_t)c * CLEN) * (DDIM / 4) + d4;
    const size_t cbase = ((size_t)b * NCH + c) * DDIM + (size_t)d4 * 4;
    f32x4 v, x;
#pragma unroll
    for (int j = 0; j < 4; j++) {
        float2 cr = carry[cbase + j];
        v[j] = cr.x; x[j] = cr.y;
    }
    for (int i = 0; i < CLEN; i++) {
        f32x4 Av = A4[idx], pv = PREV4[idx], dtv = DTX4[idx];
#pragma unroll
        for (int j = 0; j < 4; j++) {
            v[j] = fmaf(Av[j], v[j], pv[j] * dtv[j]);
            x[j] = fmaf(dtv[j], v[j], x[j]);
        }
        PREV4[idx] = v;
        DTX4[idx] = x;
        idx += DDIM / 4;
    }
}

extern "C" void kernel_launch(void* const* d_in, const int* in_sizes, int n_in,
                              void* d_out, int out_size, void* d_ws, size_t ws_size,
                              hipStream_t stream) {
    const float* force = (const float*)d_in[2];
    const float* WA  = (const float*)d_in[5];
    const float* bA  = (const float*)d_in[6];
    const float* WB  = (const float*)d_in[7];
    const float* bB  = (const float*)d_in[8];
    const float* Wdt = (const float*)d_in[9];
    const float* bdt = (const float*)d_in[10];

    float* xseq = (float*)d_out;                          // [B,L,D] first output
    float* vseq = xseq + (size_t)MROWS * DDIM;            // [B,L,D] second output

    char* ws = (char*)d_ws;
    float*  wsA   = (float*) ws;                             // 64 MB: A gates (live to end)
    ushort* Fb    = (ushort*)(ws + ((size_t)64  << 20));     // 32 MB: bf16 force (dead after gemm)
    ushort* Wcat  = (ushort*)(ws + ((size_t)96  << 20));     //  6 MB: bf16 [WA;WB;Wdt]
    // summ/carry reuse the Fb region (only written after gemm completes):
    float4* summ  = (float4*)(ws + ((size_t)64  << 20));     //  8 MB: chunk summaries
    float2* carry = (float2*)(ws + ((size_t)72  << 20));     //  4 MB: chunk carries

    const int n4_force = MROWS * DDIM / 4;     // 4194304

    cvt4<<<n4_force / 256, 256, 0, stream>>>(force, Fb, n4_force);
    cvt4_w3<<<3 * N4W / 256, 256, 0, stream>>>(WA, WB, Wdt, Wcat);

    gemm_fused<<<768, 512, 0, stream>>>(Fb, Wcat, bA, bB, bdt,
                                        wsA, vseq, xseq);

    scan_pass1<<<BDIM * NCH, 256, 0, stream>>>(wsA, vseq, xseq, summ);
    scan_pass2<<<16, 256, 0, stream>>>(summ, carry);
    scan_pass3<<<BDIM * NCH, 256, 0, stream>>>(wsA, vseq, xseq, carry);
}

// Round 8
// 320.032 us; speedup vs baseline: 1.0508x; 1.0508x over previous
//
#include <hip/hip_runtime.h>
#include <hip/hip_bf16.h>
#include <math.h>

// ParallelMLayer: x_seq, v_seq = scan over A=sigmoid(F@WA.T+bA),
// dt=softplus(F@Wdt.T+bdt)*0.1*1.5^(d/128), B=(F@WB.T+bB)*dt
// v_t = A_t v_{t-1} + B_t ; x_t = x_{t-1} + dt_t * v_t
//
// R8: GEMM ported to the verified 8-phase counted-vmcnt template (m201-style):
// 256x256 tile, BK=32, 8 waves, LDS 64KB (2-parity x 2-half x 128x32 per mat).
// Per phase: ds-reads + 1 gload_lds stage + [vmcnt(2) @ph4/ph8, never 0] +
// raw s_barrier + setprio-wrapped 8 MFMA + s_barrier. XOR-swizzled staging.

#define BDIM 4
#define LSEQ 4096
#define DDIM 1024
#define MROWS (BDIM*LSEQ)   // 16384
#define NCH 128             // scan chunks per sequence
#define CLEN (LSEQ/NCH)     // 32
#define N4W (DDIM*DDIM/4)   // 262144 (2^18)

typedef __attribute__((ext_vector_type(8))) short s16x8;
typedef __attribute__((ext_vector_type(4))) float f32x4;

__device__ inline ushort f2bf(float f) {
    unsigned u = __builtin_bit_cast(unsigned, f);
    unsigned r = (u + 0x7fffu + ((u >> 16) & 1u)) >> 16;
    return (ushort)r;
}

__device__ inline void gld_lds16(const ushort* g, ushort* l) {
    __builtin_amdgcn_global_load_lds(
        (const __attribute__((address_space(1))) void*)g,
        (__attribute__((address_space(3))) void*)l, 16, 0, 0);
}

// ---- f32 -> bf16 conversion, 4 elems/thread ----
__global__ void cvt4(const float* __restrict__ src, ushort* __restrict__ dst, int n4) {
    int i = blockIdx.x * 256 + threadIdx.x;
    if (i >= n4) return;
    float4 v = reinterpret_cast<const float4*>(src)[i];
    ushort4 o;
    o.x = f2bf(v.x); o.y = f2bf(v.y); o.z = f2bf(v.z); o.w = f2bf(v.w);
    reinterpret_cast<ushort4*>(dst)[i] = o;
}

// ---- three equal-size weight matrices -> one concatenated bf16 buffer ----
__global__ void cvt4_w3(const float* __restrict__ s0, const float* __restrict__ s1,
                        const float* __restrict__ s2, ushort* __restrict__ dst) {
    int i = blockIdx.x * 256 + threadIdx.x;      // 0 .. 3*N4W-1
    int w = i >> 18;                             // N4W = 2^18
    int j = i & (N4W - 1);
    const float* s = (w == 0) ? s0 : (w == 1) ? s1 : s2;
    float4 v = reinterpret_cast<const float4*>(s)[j];
    ushort4 o;
    o.x = f2bf(v.x); o.y = f2bf(v.y); o.z = f2bf(v.z); o.w = f2bf(v.w);
    reinterpret_cast<ushort4*>(dst)[i] = o;
}

// One 8-phase sub-step. par/q are compile-time literals (rule #20).
// Reads of As/Bs[par] are of data staged >=4 phases ago (vmcnt-retired).
// Stage targets a buffer whose last ds_read completed >=1 barrier-pair ago:
//   ph1/2 stage A(par1): last read prev-iter ph8.   ph3/4 stage B(par0): last read ph1.
//   ph5/6 stage A(par0): last read ph4.             ph7/8 stage B(par1): last read ph5.
#define PHASE(par, q, ssrc, sdst, vmw)                                              \
  {                                                                                 \
    if ((q) == 0) {                                                                 \
      _Pragma("unroll")                                                             \
      for (int n = 0; n < 4; n++)                                                   \
        bfr[n] = *reinterpret_cast<const s16x8*>(                                   \
            &Bs[(par) * 8192 + bHalfOff + n * 512 + rdBase]);                       \
    }                                                                               \
    s16x8 af0 = *reinterpret_cast<const s16x8*>(                                    \
        &As[(par) * 8192 + aHalfOff + (2 * (q)) * 512 + rdBase]);                   \
    s16x8 af1 = *reinterpret_cast<const s16x8*>(                                    \
        &As[(par) * 8192 + aHalfOff + (2 * (q) + 1) * 512 + rdBase]);               \
    gld_lds16((ssrc), (sdst));                                                      \
    if (vmw) asm volatile("s_waitcnt vmcnt(2)" ::: "memory");                       \
    asm volatile("" ::: "memory");                                                  \
    __builtin_amdgcn_s_barrier();                                                   \
    asm volatile("" ::: "memory");                                                  \
    __builtin_amdgcn_s_setprio(1);                                                  \
    _Pragma("unroll")                                                               \
    for (int n = 0; n < 4; n++) {                                                   \
      acc[2 * (q)][n]     = __builtin_amdgcn_mfma_f32_16x16x32_bf16(af0, bfr[n], acc[2 * (q)][n], 0, 0, 0);     \
      acc[2 * (q) + 1][n] = __builtin_amdgcn_mfma_f32_16x16x32_bf16(af1, bfr[n], acc[2 * (q) + 1][n], 0, 0, 0); \
    }                                                                               \
    __builtin_amdgcn_s_setprio(0);                                                  \
    asm volatile("" ::: "memory");                                                  \
    __builtin_amdgcn_s_barrier();                                                   \
    asm volatile("" ::: "memory");                                                  \
  }

// ---- fused GEMM: C[i][j] = sum_k F[i][k] * Wcat[j][k] ----
__global__ __launch_bounds__(512) void gemm_fused(
    const ushort* __restrict__ F, const ushort* __restrict__ Wc,
    const float* __restrict__ biasA, const float* __restrict__ biasB,
    const float* __restrict__ biasDt,
    float* __restrict__ outA, float* __restrict__ outPre, float* __restrict__ outDt)
{
    __shared__ ushort As[16384];   // [par][half][128][32] bf16 = 32 KB
    __shared__ ushort Bs[16384];   // 32 KB
    const int t = threadIdx.x;
    // XCD-aware swizzle (768 % 8 == 0 -> bijective)
    const int swz = (blockIdx.x & 7) * 96 + (blockIdx.x >> 3);
    const int bi = swz / 12;     // 0..63  M tiles
    const int bj = swz % 12;     // 0..11  N tiles
    const int lane = t & 63, wid = t >> 6;
    const int wm = wid >> 2, wn = wid & 3;   // 2x4 waves, each 128x64 out
    const int lr = lane & 15, lg = lane >> 4;

    // ---- staging source pointers (pre-swizzled, R5-proven pattern) ----
    // Per half-tile gload: wave wid covers rows wid*16 + (lane>>2); physical
    // chunk lane&3 holds global chunk (lane&3)^((lane>>3)&3).
    const int srow = wid * 16 + (lane >> 2);
    const int gchunk = ((lane & 3) ^ ((lane >> 3) & 3)) * 8;
    const ushort* pA0 = F  + ((size_t)bi * 256 + srow) * DDIM + gchunk;
    const ushort* pA1 = pA0 + (size_t)128 * DDIM;
    const ushort* pB0 = Wc + ((size_t)bj * 256 + srow) * DDIM + gchunk;
    const ushort* pB1 = pB0 + (size_t)128 * DDIM;
    // LDS dests (wave-uniform; HW adds lane*16B)
    ushort* dA[2][2]; ushort* dB[2][2];
#pragma unroll
    for (int p = 0; p < 2; p++)
#pragma unroll
        for (int h = 0; h < 2; h++) {
            dA[p][h] = As + p * 8192 + h * 4096 + wid * 512;
            dB[p][h] = Bs + p * 8192 + h * 4096 + wid * 512;
        }

    // ---- read-side constants ----
    // frag addr (row-in-half = X*16+lr): X*512 + lr*32 + (lg ^ ((lr>>1)&3))*8
    const int rdBase = lr * 32 + ((lg ^ ((lr >> 1) & 3)) * 8);
    const int aHalfOff = wm * 4096;                      // wm selects A half
    const int bHalfOff = (wn >> 1) * 4096 + (wn & 1) * 2048;  // row = (wn&1)*64 + n*16+lr

    f32x4 acc[8][4] = {};
    s16x8 bfr[4];

    // ---- prologue: stage B(T0), A(T0), B(T1); vmcnt(2); barrier ----
    gld_lds16(pB0, dB[0][0]);
    gld_lds16(pB1, dB[0][1]);
    gld_lds16(pA0, dA[0][0]);
    gld_lds16(pA1, dA[0][1]);
    gld_lds16(pB0 + 32, dB[1][0]);
    gld_lds16(pB1 + 32, dB[1][1]);
    asm volatile("s_waitcnt vmcnt(2)" ::: "memory");
    asm volatile("" ::: "memory");
    __builtin_amdgcn_s_barrier();
    asm volatile("" ::: "memory");

    // ---- main loop: 16 iters x 8 phases; K-tiles Ta=2i (par0), Tb=2i+1 (par1)
    for (int it = 0; it < 16; ++it) {
        const int t1 = 2 * it + 1;
        const int t2 = (2 * it + 2 > 31) ? 31 : 2 * it + 2;
        const int t3 = (2 * it + 3 > 31) ? 31 : 2 * it + 3;
        PHASE(0, 0, pA0 + t1 * 32, dA[1][0], false)
        PHASE(0, 1, pA1 + t1 * 32, dA[1][1], false)
        PHASE(0, 2, pB0 + t2 * 32, dB[0][0], false)
        PHASE(0, 3, pB1 + t2 * 32, dB[0][1], true)
        PHASE(1, 0, pA0 + t2 * 32, dA[0][0], false)
        PHASE(1, 1, pA1 + t2 * 32, dA[0][1], false)
        PHASE(1, 2, pB0 + t3 * 32, dB[1][0], false)
        PHASE(1, 3, pB1 + t3 * 32, dB[1][1], true)
    }

    // ---- epilogue: C/D layout col=lane&15, row=(lane>>4)*4+reg ----
    const int mat = bj >> 2;                     // 0:A 1:B-pre 2:dt
    const int colBase = (bj & 3) * 256 + wn * 64;
    const size_t rowBase = (size_t)bi * 256 + wm * 128;

    if (mat == 0) {
#pragma unroll
        for (int n = 0; n < 4; n++) {
            const int d = colBase + n * 16 + lr;
            const float bb = biasA[d];
#pragma unroll
            for (int m = 0; m < 8; m++)
#pragma unroll
                for (int rix = 0; rix < 4; rix++) {
                    const size_t row = rowBase + m * 16 + lg * 4 + rix;
                    float s = acc[m][n][rix] + bb;
                    outA[row * DDIM + d] = 1.0f / (1.0f + expf(-s));
                }
        }
    } else if (mat == 1) {
#pragma unroll
        for (int n = 0; n < 4; n++) {
            const int d = colBase + n * 16 + lr;
            const float bb = biasB[d];
#pragma unroll
            for (int m = 0; m < 8; m++)
#pragma unroll
                for (int rix = 0; rix < 4; rix++) {
                    const size_t row = rowBase + m * 16 + lg * 4 + rix;
                    outPre[row * DDIM + d] = acc[m][n][rix] + bb;
                }
        }
    } else {
#pragma unroll
        for (int n = 0; n < 4; n++) {
            const int d = colBase + n * 16 + lr;
            const float bb = biasDt[d];
            const float scl = 0.1f * exp2f(0.58496250072f * (float)(d >> 7)); // 0.1*1.5^(d/128)
#pragma unroll
            for (int m = 0; m < 8; m++)
#pragma unroll
                for (int rix = 0; rix < 4; rix++) {
                    const size_t row = rowBase + m * 16 + lg * 4 + rix;
                    float s = acc[m][n][rix] + bb;
                    float sp = fmaxf(s, 0.0f) + log1pf(expf(-fabsf(s)));
                    outDt[row * DDIM + d] = sp * scl;
                }
        }
    }
}

// ---- scan pass 1: per (b, chunk, d) composite map (a, c, bv, bx), float4 ----
__global__ void scan_pass1(const float* __restrict__ A, const float* __restrict__ PRE,
                           const float* __restrict__ DT, float4* __restrict__ summ)
{
    const int c = blockIdx.x & (NCH - 1);
    const int b = blockIdx.x >> 7;       // NCH = 128
    const int d4 = threadIdx.x;          // 0..255, covers d = 4*d4..+3
    const f32x4* A4   = (const f32x4*)A;
    const f32x4* PRE4 = (const f32x4*)PRE;
    const f32x4* DT4  = (const f32x4*)DT;
    size_t idx = ((size_t)b * LSEQ + (size_t)c * CLEN) * (DDIM / 4) + d4;
    f32x4 a = {1.f,1.f,1.f,1.f}, cc = {}, bv = {}, bx = {};
    for (int i = 0; i < CLEN; i++) {
        f32x4 Av = A4[idx], pv = PRE4[idx], dtv = DT4[idx];
#pragma unroll
        for (int j = 0; j < 4; j++) {
            a[j] *= Av[j];
            cc[j] = fmaf(dtv[j], a[j], cc[j]);
            bv[j] = fmaf(Av[j], bv[j], pv[j] * dtv[j]);
            bx[j] = fmaf(dtv[j], bv[j], bx[j]);
        }
        idx += DDIM / 4;
    }
    const size_t base = ((size_t)b * NCH + c) * DDIM + (size_t)d4 * 4;
#pragma unroll
    for (int j = 0; j < 4; j++)
        summ[base + j] = make_float4(a[j], cc[j], bv[j], bx[j]);
}

// ---- scan pass 2: serial over chunks per channel -> carry-in (v, x) ----
__global__ void scan_pass2(const float4* __restrict__ summ, float2* __restrict__ carry)
{
    const int idx = blockIdx.x * 256 + threadIdx.x;   // 4096 channels
    const int b = idx >> 10, d = idx & 1023;
    float v = 0.0f, x = 0.0f;
    for (int c = 0; c < NCH; c++) {
        const size_t o = ((size_t)b * NCH + c) * DDIM + d;
        carry[o] = make_float2(v, x);
        float4 s = summ[o];
        x = x + s.y * v + s.w;   // x' = x + c*v + bx (uses OLD v)
        v = s.x * v + s.z;       // v' = a*v + bv
    }
}

// ---- scan pass 3: finalize with carry; in-place pre->v_seq, dt->x_seq ----
__global__ void scan_pass3(const float* __restrict__ A, float* __restrict__ PREV,
                           float* __restrict__ DTX, const float2* __restrict__ carry)
{
    const int c = blockIdx.x & (NCH - 1);
    const int b = blockIdx.x >> 7;
    const int d4 = threadIdx.x;
    const f32x4* A4 = (const f32x4*)A;
    f32x4* PREV4 = (f32x4*)PREV;
    f32x4* DTX4  = (f32x4*)DTX;
    size_t idx = ((size_t)b * LSEQ + (size_t)c * CLEN) * (DDIM / 4) + d4;
    const size_t cbase = ((size_t)b * NCH + c) * DDIM + (size_t)d4 * 4;
    f32x4 v, x;
#pragma unroll
    for (int j = 0; j < 4; j++) {
        float2 cr = carry[cbase + j];
        v[j] = cr.x; x[j] = cr.y;
    }
    for (int i = 0; i < CLEN; i++) {
        f32x4 Av = A4[idx], pv = PREV4[idx], dtv = DTX4[idx];
#pragma unroll
        for (int j = 0; j < 4; j++) {
            v[j] = fmaf(Av[j], v[j], pv[j] * dtv[j]);
            x[j] = fmaf(dtv[j], v[j], x[j]);
        }
        PREV4[idx] = v;
        DTX4[idx] = x;
        idx += DDIM / 4;
    }
}

extern "C" void kernel_launch(void* const* d_in, const int* in_sizes, int n_in,
                              void* d_out, int out_size, void* d_ws, size_t ws_size,
                              hipStream_t stream) {
    const float* force = (const float*)d_in[2];
    const float* WA  = (const float*)d_in[5];
    const float* bA  = (const float*)d_in[6];
    const float* WB  = (const float*)d_in[7];
    const float* bB  = (const float*)d_in[8];
    const float* Wdt = (const float*)d_in[9];
    const float* bdt = (const float*)d_in[10];

    float* xseq = (float*)d_out;                          // [B,L,D] first output
    float* vseq = xseq + (size_t)MROWS * DDIM;            // [B,L,D] second output

    char* ws = (char*)d_ws;
    float*  wsA   = (float*) ws;                             // 64 MB: A gates (live to end)
    ushort* Fb    = (ushort*)(ws + ((size_t)64  << 20));     // 32 MB: bf16 force (dead after gemm)
    ushort* Wcat  = (ushort*)(ws + ((size_t)96  << 20));     //  6 MB: bf16 [WA;WB;Wdt]
    // summ/carry reuse the Fb region (only written after gemm completes):
    float4* summ  = (float4*)(ws + ((size_t)64  << 20));     //  8 MB: chunk summaries
    float2* carry = (float2*)(ws + ((size_t)72  << 20));     //  4 MB: chunk carries

    const int n4_force = MROWS * DDIM / 4;     // 4194304

    cvt4<<<n4_force / 256, 256, 0, stream>>>(force, Fb, n4_force);
    cvt4_w3<<<3 * N4W / 256, 256, 0, stream>>>(WA, WB, Wdt, Wcat);

    gemm_fused<<<768, 512, 0, stream>>>(Fb, Wcat, bA, bB, bdt,
                                        wsA, vseq, xseq);

    scan_pass1<<<BDIM * NCH, 256, 0, stream>>>(wsA, vseq, xseq, summ);
    scan_pass2<<<16, 256, 0, stream>>>(summ, carry);
    scan_pass3<<<BDIM * NCH, 256, 0, stream>>>(wsA, vseq, xseq, carry);
}

// Round 9
// 289.197 us; speedup vs baseline: 1.1628x; 1.1066x over previous
//
#include <hip/hip_runtime.h>
#include <hip/hip_bf16.h>
#include <math.h>

// ParallelMLayer: x_seq, v_seq = scan over A=sigmoid(F@WA.T+bA),
// dt=softplus(F@Wdt.T+bdt)*0.1*1.5^(d/128), B=(F@WB.T+bB)*dt
// v_t = A_t v_{t-1} + B_t ; x_t = x_{t-1} + dt_t * v_t
//
// R9: GEMM (R5 structure) now emits fp16 PREACTIVATIONS only (bias added);
// sigmoid/softplus moved into the BW-bound scan passes (idle VALU there).
// Output traffic 192->96 MB, scan read traffic halved. Buffers: sA/sB/sDt
// fp16 in ws; bf16 force staged in x_seq region, Wcat in v_seq region
// (both dead before pass3 overwrites d_out).

#define BDIM 4
#define LSEQ 4096
#define DDIM 1024
#define MROWS (BDIM*LSEQ)   // 16384
#define NCH 128             // scan chunks per sequence
#define CLEN (LSEQ/NCH)     // 32
#define N4W (DDIM*DDIM/4)   // 262144 (2^18)
#define BK 64

typedef __attribute__((ext_vector_type(8))) unsigned short u16x8;
typedef __attribute__((ext_vector_type(8))) short s16x8;
typedef __attribute__((ext_vector_type(4))) float f32x4;

__device__ inline ushort f2bf(float f) {
    unsigned u = __builtin_bit_cast(unsigned, f);
    unsigned r = (u + 0x7fffu + ((u >> 16) & 1u)) >> 16;
    return (ushort)r;
}
__device__ inline ushort f2h(float f) {
    return __builtin_bit_cast(ushort, (_Float16)f);
}
__device__ inline float h2f(ushort u) {
    return (float)__builtin_bit_cast(_Float16, u);
}

__device__ inline void gld_lds16(const ushort* g, ushort* l) {
    __builtin_amdgcn_global_load_lds(
        (const __attribute__((address_space(1))) void*)g,
        (__attribute__((address_space(3))) void*)l, 16, 0, 0);
}

// ---- f32 -> bf16 conversion, 4 elems/thread ----
__global__ void cvt4(const float* __restrict__ src, ushort* __restrict__ dst, int n4) {
    int i = blockIdx.x * 256 + threadIdx.x;
    if (i >= n4) return;
    float4 v = reinterpret_cast<const float4*>(src)[i];
    ushort4 o;
    o.x = f2bf(v.x); o.y = f2bf(v.y); o.z = f2bf(v.z); o.w = f2bf(v.w);
    reinterpret_cast<ushort4*>(dst)[i] = o;
}

// ---- three equal-size weight matrices -> one concatenated bf16 buffer ----
__global__ void cvt4_w3(const float* __restrict__ s0, const float* __restrict__ s1,
                        const float* __restrict__ s2, ushort* __restrict__ dst) {
    int i = blockIdx.x * 256 + threadIdx.x;      // 0 .. 3*N4W-1
    int w = i >> 18;                             // N4W = 2^18
    int j = i & (N4W - 1);
    const float* s = (w == 0) ? s0 : (w == 1) ? s1 : s2;
    float4 v = reinterpret_cast<const float4*>(s)[j];
    ushort4 o;
    o.x = f2bf(v.x); o.y = f2bf(v.y); o.z = f2bf(v.z); o.w = f2bf(v.w);
    reinterpret_cast<ushort4*>(dst)[i] = o;
}

// ---- fused GEMM: S[i][j] = sum_k F[i][k] * Wcat[j][k] + bias[j] -> fp16 ----
// R5 structure: 128x128 tile, BK=64, gload_lds(16B) with pre-swizzled source
// (chunk c^(R&7)) + same XOR on ds_read -> 0 bank conflicts (verified R5).
__global__ __launch_bounds__(256) void gemm_fused(
    const ushort* __restrict__ F, const ushort* __restrict__ Wc,
    const float* __restrict__ biasA, const float* __restrict__ biasB,
    const float* __restrict__ biasDt,
    ushort* __restrict__ sA, ushort* __restrict__ sB, ushort* __restrict__ sDt)
{
    __shared__ ushort As[128 * BK];   // 16 KB
    __shared__ ushort Bs[128 * BK];   // 16 KB
    const int t = threadIdx.x;
    const int bi = blockIdx.x;   // 0..127 M tiles
    const int bj = blockIdx.y;   // 0..23  N tiles
    const int lane = t & 63, wid = t >> 6;
    const int wm = wid >> 1, wn = wid & 1;   // 2x2 waves, each 64x64 out
    const int lr = lane & 15, lg = lane >> 4;
    const int rr = lane >> 3;    // row-within-8 for staging
    const int cc = lane & 7;     // 16B chunk 0..7 for staging

    const size_t aBase = (size_t)bi * 128;
    const size_t bBase = (size_t)bj * 128;

    const ushort* gA[4]; const ushort* gB[4];
    int off[4];
#pragma unroll
    for (int i = 0; i < 4; i++) {
        const int R = i * 32 + wid * 8 + rr;
        const int sw = (cc ^ (R & 7)) * 8;
        gA[i] = F  + (aBase + R) * DDIM + sw;
        gB[i] = Wc + (bBase + R) * DDIM + sw;
        off[i] = (i * 32 + wid * 8) * BK;  // wave-uniform base; HW adds lane*16B
    }

    f32x4 acc[4][4] = {};

    for (int k0 = 0; k0 < DDIM; k0 += BK) {
        __syncthreads();
#pragma unroll
        for (int i = 0; i < 4; i++) gld_lds16(gA[i] + k0, &As[off[i]]);
#pragma unroll
        for (int i = 0; i < 4; i++) gld_lds16(gB[i] + k0, &Bs[off[i]]);
        __syncthreads();
#pragma unroll
        for (int kk = 0; kk < 2; kk++) {
            s16x8 af[4], bf[4];
#pragma unroll
            for (int m = 0; m < 4; m++) {
                const int r = wm * 64 + m * 16 + lr;
                const int p = (kk * 4 + lg) ^ (lr & 7);   // un-swizzle on read
                af[m] = *reinterpret_cast<const s16x8*>(&As[r * BK + p * 8]);
            }
#pragma unroll
            for (int n = 0; n < 4; n++) {
                const int r = wn * 64 + n * 16 + lr;
                const int p = (kk * 4 + lg) ^ (lr & 7);
                bf[n] = *reinterpret_cast<const s16x8*>(&Bs[r * BK + p * 8]);
            }
#pragma unroll
            for (int m = 0; m < 4; m++)
#pragma unroll
                for (int n = 0; n < 4; n++)
                    acc[m][n] = __builtin_amdgcn_mfma_f32_16x16x32_bf16(af[m], bf[n], acc[m][n], 0, 0, 0);
        }
    }

    // epilogue: bias-add + fp16 store only. C/D: col=lane&15, row=(lane>>4)*4+reg
    const int mat = bj >> 3;                     // 0:A 1:B 2:dt
    const int colBase = (bj & 7) * 128 + wn * 64;
    const size_t rowBase = (size_t)bi * 128 + wm * 64;
    const float* bias = (mat == 0) ? biasA : (mat == 1) ? biasB : biasDt;
    ushort* outp = (mat == 0) ? sA : (mat == 1) ? sB : sDt;

#pragma unroll
    for (int n = 0; n < 4; n++) {
        const int d = colBase + n * 16 + lr;
        const float bb = bias[d];
#pragma unroll
        for (int m = 0; m < 4; m++)
#pragma unroll
            for (int r = 0; r < 4; r++) {
                const size_t row = rowBase + m * 16 + lg * 4 + r;
                outp[row * DDIM + d] = f2h(acc[m][n][r] + bb);
            }
    }
}

// activation helpers (scan-side)
__device__ inline float sigm(float s) { return 1.0f / (1.0f + __expf(-s)); }
__device__ inline float softp(float s) {
    return fmaxf(s, 0.0f) + log1pf(__expf(-fabsf(s)));
}

// ---- scan pass 1: per (b, chunk, d) composite map (a, c, bv, bx) ----
__global__ void scan_pass1(const ushort* __restrict__ sA, const ushort* __restrict__ sB,
                           const ushort* __restrict__ sDt, float4* __restrict__ summ)
{
    const int c = blockIdx.x & (NCH - 1);
    const int b = blockIdx.x >> 7;       // NCH = 128
    const int d4 = threadIdx.x;          // 0..255, covers d = 4*d4..+3
    size_t idx4 = ((size_t)b * LSEQ + (size_t)c * CLEN) * (DDIM / 4) + d4;
    const float scl = 0.1f * exp2f(0.58496250072f * (float)(d4 >> 5)); // 0.1*1.5^(d>>7)
    float a[4] = {1.f,1.f,1.f,1.f}, cc[4] = {}, bv[4] = {}, bx[4] = {};
    for (int i = 0; i < CLEN; i++) {
        ushort4 ua = reinterpret_cast<const ushort4*>(sA)[idx4];
        ushort4 ub = reinterpret_cast<const ushort4*>(sB)[idx4];
        ushort4 ud = reinterpret_cast<const ushort4*>(sDt)[idx4];
        const ushort va[4] = {ua.x, ua.y, ua.z, ua.w};
        const ushort vb[4] = {ub.x, ub.y, ub.z, ub.w};
        const ushort vd[4] = {ud.x, ud.y, ud.z, ud.w};
#pragma unroll
        for (int j = 0; j < 4; j++) {
            const float A  = sigm(h2f(va[j]));
            const float dt = softp(h2f(vd[j])) * scl;
            const float bval = h2f(vb[j]) * dt;
            a[j] *= A;
            cc[j] = fmaf(dt, a[j], cc[j]);
            bv[j] = fmaf(A, bv[j], bval);
            bx[j] = fmaf(dt, bv[j], bx[j]);
        }
        idx4 += DDIM / 4;
    }
    const size_t base = ((size_t)b * NCH + c) * DDIM + (size_t)d4 * 4;
#pragma unroll
    for (int j = 0; j < 4; j++)
        summ[base + j] = make_float4(a[j], cc[j], bv[j], bx[j]);
}

// ---- scan pass 2: serial over chunks per channel -> carry-in (v, x) ----
__global__ void scan_pass2(const float4* __restrict__ summ, float2* __restrict__ carry)
{
    const int idx = blockIdx.x * 256 + threadIdx.x;   // 4096 channels
    const int b = idx >> 10, d = idx & 1023;
    float v = 0.0f, x = 0.0f;
    for (int c = 0; c < NCH; c++) {
        const size_t o = ((size_t)b * NCH + c) * DDIM + d;
        carry[o] = make_float2(v, x);
        float4 s = summ[o];
        x = x + s.y * v + s.w;   // x' = x + c*v + bx (uses OLD v)
        v = s.x * v + s.z;       // v' = a*v + bv
    }
}

// ---- scan pass 3: finalize with carry; write v_seq/x_seq fp32 ----
__global__ void scan_pass3(const ushort* __restrict__ sA, const ushort* __restrict__ sB,
                           const ushort* __restrict__ sDt, const float2* __restrict__ carry,
                           float* __restrict__ VS, float* __restrict__ XS)
{
    const int c = blockIdx.x & (NCH - 1);
    const int b = blockIdx.x >> 7;
    const int d4 = threadIdx.x;
    size_t idx4 = ((size_t)b * LSEQ + (size_t)c * CLEN) * (DDIM / 4) + d4;
    const float scl = 0.1f * exp2f(0.58496250072f * (float)(d4 >> 5));
    const size_t cbase = ((size_t)b * NCH + c) * DDIM + (size_t)d4 * 4;
    f32x4 v, x;
#pragma unroll
    for (int j = 0; j < 4; j++) {
        float2 cr = carry[cbase + j];
        v[j] = cr.x; x[j] = cr.y;
    }
    f32x4* VS4 = (f32x4*)VS;
    f32x4* XS4 = (f32x4*)XS;
    for (int i = 0; i < CLEN; i++) {
        ushort4 ua = reinterpret_cast<const ushort4*>(sA)[idx4];
        ushort4 ub = reinterpret_cast<const ushort4*>(sB)[idx4];
        ushort4 ud = reinterpret_cast<const ushort4*>(sDt)[idx4];
        const ushort va[4] = {ua.x, ua.y, ua.z, ua.w};
        const ushort vb[4] = {ub.x, ub.y, ub.z, ub.w};
        const ushort vd[4] = {ud.x, ud.y, ud.z, ud.w};
#pragma unroll
        for (int j = 0; j < 4; j++) {
            const float A  = sigm(h2f(va[j]));
            const float dt = softp(h2f(vd[j])) * scl;
            v[j] = fmaf(A, v[j], h2f(vb[j]) * dt);
            x[j] = fmaf(dt, v[j], x[j]);
        }
        VS4[idx4] = v;
        XS4[idx4] = x;
        idx4 += DDIM / 4;
    }
}

extern "C" void kernel_launch(void* const* d_in, const int* in_sizes, int n_in,
                              void* d_out, int out_size, void* d_ws, size_t ws_size,
                              hipStream_t stream) {
    const float* force = (const float*)d_in[2];
    const float* WA  = (const float*)d_in[5];
    const float* bA  = (const float*)d_in[6];
    const float* WB  = (const float*)d_in[7];
    const float* bB  = (const float*)d_in[8];
    const float* Wdt = (const float*)d_in[9];
    const float* bdt = (const float*)d_in[10];

    float* xseq = (float*)d_out;                          // [B,L,D] first output
    float* vseq = xseq + (size_t)MROWS * DDIM;            // [B,L,D] second output

    // bf16 staging buffers live in d_out (dead before pass3 writes there):
    ushort* Fb   = (ushort*)xseq;   // 32 MB bf16 force in x region
    ushort* Wcat = (ushort*)vseq;   //  6 MB bf16 [WA;WB;Wdt] in v region

    char* ws = (char*)d_ws;
    ushort* sA    = (ushort*) ws;                            // 32 MB fp16 A preact
    ushort* sB    = (ushort*)(ws + ((size_t)32 << 20));      // 32 MB fp16 B preact
    ushort* sDt   = (ushort*)(ws + ((size_t)64 << 20));      // 32 MB fp16 dt preact
    float4* summ  = (float4*)(ws + ((size_t)96 << 20));      //  8 MB chunk summaries
    float2* carry = (float2*)(ws + ((size_t)104 << 20));     //  4 MB chunk carries (ends 108 MB)

    const int n4_force = MROWS * DDIM / 4;     // 4194304

    cvt4<<<n4_force / 256, 256, 0, stream>>>(force, Fb, n4_force);
    cvt4_w3<<<3 * N4W / 256, 256, 0, stream>>>(WA, WB, Wdt, Wcat);

    gemm_fused<<<dim3(128, 24), 256, 0, stream>>>(Fb, Wcat, bA, bB, bdt,
                                                  sA, sB, sDt);

    scan_pass1<<<BDIM * NCH, 256, 0, stream>>>(sA, sB, sDt, summ);
    scan_pass2<<<16, 256, 0, stream>>>(summ, carry);
    scan_pass3<<<BDIM * NCH, 256, 0, stream>>>(sA, sB, sDt, carry, vseq, xseq);
}

// Round 11
// 219.713 us; speedup vs baseline: 1.5305x; 1.3163x over previous
//
#include <hip/hip_runtime.h>
#include <hip/hip_bf16.h>
#include <math.h>

// ParallelMLayer: x_seq, v_seq = scan over A=sigmoid(F@WA.T+bA),
// dt=softplus(F@Wdt.T+bdt)*0.1*1.5^(d/128), B=(F@WB.T+bB)*dt
// v_t = A_t v_{t-1} + B_t ; x_t = x_{t-1} + dt_t * v_t
//
// R10: R9 pipeline; scan-side activations switched to HW transcendentals
// (v_exp/v_log/v_rcp instead of log1pf + exact div) — the R9 post-mortem
// showed precise-libm softplus/sigmoid cost ~45us across pass1+pass3.
// cvt kernels merged into one launch.

#define BDIM 4
#define LSEQ 4096
#define DDIM 1024
#define MROWS (BDIM*LSEQ)   // 16384
#define NCH 128             // scan chunks per sequence
#define CLEN (LSEQ/NCH)     // 32
#define N4W (DDIM*DDIM/4)   // 262144 (2^18)
#define N4F (MROWS*DDIM/4)  // 4194304
#define BK 64

typedef __attribute__((ext_vector_type(8))) unsigned short u16x8;
typedef __attribute__((ext_vector_type(8))) short s16x8;
typedef __attribute__((ext_vector_type(4))) float f32x4;

__device__ inline ushort f2bf(float f) {
    unsigned u = __builtin_bit_cast(unsigned, f);
    unsigned r = (u + 0x7fffu + ((u >> 16) & 1u)) >> 16;
    return (ushort)r;
}
__device__ inline ushort f2h(float f) {
    return __builtin_bit_cast(ushort, (_Float16)f);
}
__device__ inline float h2f(ushort u) {
    return (float)__builtin_bit_cast(_Float16, u);
}

__device__ inline void gld_lds16(const ushort* g, ushort* l) {
    __builtin_amdgcn_global_load_lds(
        (const __attribute__((address_space(1))) void*)g,
        (__attribute__((address_space(3))) void*)l, 16, 0, 0);
}

// ---- fused f32 -> bf16 conversion: force (N4F float4s) + WA/WB/Wdt ----
__global__ void cvt_all(const float* __restrict__ force, const float* __restrict__ wa,
                        const float* __restrict__ wb, const float* __restrict__ wdt,
                        ushort* __restrict__ Fb, ushort* __restrict__ Wcat) {
    int i = blockIdx.x * 256 + threadIdx.x;   // 0 .. N4F + 3*N4W - 1
    const float* s; ushort* dst; int j;
    if (i < N4F) {
        s = force; dst = Fb; j = i;
    } else {
        int k = i - N4F;                      // 0 .. 3*N4W-1
        int w = k >> 18;                      // N4W = 2^18
        j = k & (N4W - 1);
        s = (w == 0) ? wa : (w == 1) ? wb : wdt;
        dst = Wcat + (size_t)w * DDIM * DDIM;
    }
    float4 v = reinterpret_cast<const float4*>(s)[j];
    ushort4 o;
    o.x = f2bf(v.x); o.y = f2bf(v.y); o.z = f2bf(v.z); o.w = f2bf(v.w);
    reinterpret_cast<ushort4*>(dst)[j] = o;
}

// ---- fused GEMM: S[i][j] = sum_k F[i][k] * Wcat[j][k] + bias[j] -> fp16 ----
// R5 structure: 128x128 tile, BK=64, gload_lds(16B) with pre-swizzled source
// (chunk c^(R&7)) + same XOR on ds_read -> 0 bank conflicts (verified R5/R9).
__global__ __launch_bounds__(256) void gemm_fused(
    const ushort* __restrict__ F, const ushort* __restrict__ Wc,
    const float* __restrict__ biasA, const float* __restrict__ biasB,
    const float* __restrict__ biasDt,
    ushort* __restrict__ sA, ushort* __restrict__ sB, ushort* __restrict__ sDt)
{
    __shared__ ushort As[128 * BK];   // 16 KB
    __shared__ ushort Bs[128 * BK];   // 16 KB
    const int t = threadIdx.x;
    const int bi = blockIdx.x;   // 0..127 M tiles
    const int bj = blockIdx.y;   // 0..23  N tiles
    const int lane = t & 63, wid = t >> 6;
    const int wm = wid >> 1, wn = wid & 1;   // 2x2 waves, each 64x64 out
    const int lr = lane & 15, lg = lane >> 4;
    const int rr = lane >> 3;    // row-within-8 for staging
    const int cc = lane & 7;     // 16B chunk 0..7 for staging

    const size_t aBase = (size_t)bi * 128;
    const size_t bBase = (size_t)bj * 128;

    const ushort* gA[4]; const ushort* gB[4];
    int off[4];
#pragma unroll
    for (int i = 0; i < 4; i++) {
        const int R = i * 32 + wid * 8 + rr;
        const int sw = (cc ^ (R & 7)) * 8;
        gA[i] = F  + (aBase + R) * DDIM + sw;
        gB[i] = Wc + (bBase + R) * DDIM + sw;
        off[i] = (i * 32 + wid * 8) * BK;  // wave-uniform base; HW adds lane*16B
    }

    f32x4 acc[4][4] = {};

    for (int k0 = 0; k0 < DDIM; k0 += BK) {
        __syncthreads();
#pragma unroll
        for (int i = 0; i < 4; i++) gld_lds16(gA[i] + k0, &As[off[i]]);
#pragma unroll
        for (int i = 0; i < 4; i++) gld_lds16(gB[i] + k0, &Bs[off[i]]);
        __syncthreads();
#pragma unroll
        for (int kk = 0; kk < 2; kk++) {
            s16x8 af[4], bf[4];
#pragma unroll
            for (int m = 0; m < 4; m++) {
                const int r = wm * 64 + m * 16 + lr;
                const int p = (kk * 4 + lg) ^ (lr & 7);   // un-swizzle on read
                af[m] = *reinterpret_cast<const s16x8*>(&As[r * BK + p * 8]);
            }
#pragma unroll
            for (int n = 0; n < 4; n++) {
                const int r = wn * 64 + n * 16 + lr;
                const int p = (kk * 4 + lg) ^ (lr & 7);
                bf[n] = *reinterpret_cast<const s16x8*>(&Bs[r * BK + p * 8]);
            }
#pragma unroll
            for (int m = 0; m < 4; m++)
#pragma unroll
                for (int n = 0; n < 4; n++)
                    acc[m][n] = __builtin_amdgcn_mfma_f32_16x16x32_bf16(af[m], bf[n], acc[m][n], 0, 0, 0);
        }
    }

    // epilogue: bias-add + fp16 store only. C/D: col=lane&15, row=(lane>>4)*4+reg
    const int mat = bj >> 3;                     // 0:A 1:B 2:dt
    const int colBase = (bj & 7) * 128 + wn * 64;
    const size_t rowBase = (size_t)bi * 128 + wm * 64;
    const float* bias = (mat == 0) ? biasA : (mat == 1) ? biasB : biasDt;
    ushort* outp = (mat == 0) ? sA : (mat == 1) ? sB : sDt;

#pragma unroll
    for (int n = 0; n < 4; n++) {
        const int d = colBase + n * 16 + lr;
        const float bb = bias[d];
#pragma unroll
        for (int m = 0; m < 4; m++)
#pragma unroll
            for (int r = 0; r < 4; r++) {
                const size_t row = rowBase + m * 16 + lg * 4 + r;
                outp[row * DDIM + d] = f2h(acc[m][n][r] + bb);
            }
    }
}

// activation helpers (scan-side) — HW transcendentals only:
// sigm: v_exp + v_rcp (~1e-7 rel err); softp: v_exp + v_log
// (err <= 2^-24 abs for large |s| where 1+z rounds to 1) — both negligible
// vs the bf16-GEMM error already in s.
__device__ inline float sigm(float s) {
    return __builtin_amdgcn_rcpf(1.0f + __expf(-s));
}
__device__ inline float softp(float s) {
    return fmaxf(s, 0.0f) + __logf(1.0f + __expf(-fabsf(s)));
}

// ---- scan pass 1: per (b, chunk, d) composite map (a, c, bv, bx) ----
__global__ void scan_pass1(const ushort* __restrict__ sA, const ushort* __restrict__ sB,
                           const ushort* __restrict__ sDt, float4* __restrict__ summ)
{
    const int c = blockIdx.x & (NCH - 1);
    const int b = blockIdx.x >> 7;       // NCH = 128
    const int d4 = threadIdx.x;          // 0..255, covers d = 4*d4..+3
    size_t idx4 = ((size_t)b * LSEQ + (size_t)c * CLEN) * (DDIM / 4) + d4;
    const float scl = 0.1f * exp2f(0.58496250072f * (float)(d4 >> 5)); // 0.1*1.5^(d>>7)
    float a[4] = {1.f,1.f,1.f,1.f}, cc[4] = {}, bv[4] = {}, bx[4] = {};
    for (int i = 0; i < CLEN; i++) {
        ushort4 ua = reinterpret_cast<const ushort4*>(sA)[idx4];
        ushort4 ub = reinterpret_cast<const ushort4*>(sB)[idx4];
        ushort4 ud = reinterpret_cast<const ushort4*>(sDt)[idx4];
        const ushort va[4] = {ua.x, ua.y, ua.z, ua.w};
        const ushort vb[4] = {ub.x, ub.y, ub.z, ub.w};
        const ushort vd[4] = {ud.x, ud.y, ud.z, ud.w};
#pragma unroll
        for (int j = 0; j < 4; j++) {
            const float A  = sigm(h2f(va[j]));
            const float dt = softp(h2f(vd[j])) * scl;
            const float bval = h2f(vb[j]) * dt;
            a[j] *= A;
            cc[j] = fmaf(dt, a[j], cc[j]);
            bv[j] = fmaf(A, bv[j], bval);
            bx[j] = fmaf(dt, bv[j], bx[j]);
        }
        idx4 += DDIM / 4;
    }
    const size_t base = ((size_t)b * NCH + c) * DDIM + (size_t)d4 * 4;
#pragma unroll
    for (int j = 0; j < 4; j++)
        summ[base + j] = make_float4(a[j], cc[j], bv[j], bx[j]);
}

// ---- scan pass 2: serial over chunks per channel -> carry-in (v, x) ----
__global__ void scan_pass2(const float4* __restrict__ summ, float2* __restrict__ carry)
{
    const int idx = blockIdx.x * 256 + threadIdx.x;   // 4096 channels
    const int b = idx >> 10, d = idx & 1023;
    float v = 0.0f, x = 0.0f;
    for (int c = 0; c < NCH; c++) {
        const size_t o = ((size_t)b * NCH + c) * DDIM + d;
        carry[o] = make_float2(v, x);
        float4 s = summ[o];
        x = x + s.y * v + s.w;   // x' = x + c*v + bx (uses OLD v)
        v = s.x * v + s.z;       // v' = a*v + bv
    }
}

// ---- scan pass 3: finalize with carry; write v_seq/x_seq fp32 ----
__global__ void scan_pass3(const ushort* __restrict__ sA, const ushort* __restrict__ sB,
                           const ushort* __restrict__ sDt, const float2* __restrict__ carry,
                           float* __restrict__ VS, float* __restrict__ XS)
{
    const int c = blockIdx.x & (NCH - 1);
    const int b = blockIdx.x >> 7;
    const int d4 = threadIdx.x;
    size_t idx4 = ((size_t)b * LSEQ + (size_t)c * CLEN) * (DDIM / 4) + d4;
    const float scl = 0.1f * exp2f(0.58496250072f * (float)(d4 >> 5));
    const size_t cbase = ((size_t)b * NCH + c) * DDIM + (size_t)d4 * 4;
    f32x4 v, x;
#pragma unroll
    for (int j = 0; j < 4; j++) {
        float2 cr = carry[cbase + j];
        v[j] = cr.x; x[j] = cr.y;
    }
    f32x4* VS4 = (f32x4*)VS;
    f32x4* XS4 = (f32x4*)XS;
    for (int i = 0; i < CLEN; i++) {
        ushort4 ua = reinterpret_cast<const ushort4*>(sA)[idx4];
        ushort4 ub = reinterpret_cast<const ushort4*>(sB)[idx4];
        ushort4 ud = reinterpret_cast<const ushort4*>(sDt)[idx4];
        const ushort va[4] = {ua.x, ua.y, ua.z, ua.w};
        const ushort vb[4] = {ub.x, ub.y, ub.z, ub.w};
        const ushort vd[4] = {ud.x, ud.y, ud.z, ud.w};
#pragma unroll
        for (int j = 0; j < 4; j++) {
            const float A  = sigm(h2f(va[j]));
            const float dt = softp(h2f(vd[j])) * scl;
            v[j] = fmaf(A, v[j], h2f(vb[j]) * dt);
            x[j] = fmaf(dt, v[j], x[j]);
        }
        VS4[idx4] = v;
        XS4[idx4] = x;
        idx4 += DDIM / 4;
    }
}

extern "C" void kernel_launch(void* const* d_in, const int* in_sizes, int n_in,
                              void* d_out, int out_size, void* d_ws, size_t ws_size,
                              hipStream_t stream) {
    const float* force = (const float*)d_in[2];
    const float* WA  = (const float*)d_in[5];
    const float* bA  = (const float*)d_in[6];
    const float* WB  = (const float*)d_in[7];
    const float* bB  = (const float*)d_in[8];
    const float* Wdt = (const float*)d_in[9];
    const float* bdt = (const float*)d_in[10];

    float* xseq = (float*)d_out;                          // [B,L,D] first output
    float* vseq = xseq + (size_t)MROWS * DDIM;            // [B,L,D] second output

    // bf16 staging buffers live in d_out (dead before pass3 writes there):
    ushort* Fb   = (ushort*)xseq;   // 32 MB bf16 force in x region
    ushort* Wcat = (ushort*)vseq;   //  6 MB bf16 [WA;WB;Wdt] in v region

    char* ws = (char*)d_ws;
    ushort* sA    = (ushort*) ws;                            // 32 MB fp16 A preact
    ushort* sB    = (ushort*)(ws + ((size_t)32 << 20));      // 32 MB fp16 B preact
    ushort* sDt   = (ushort*)(ws + ((size_t)64 << 20));      // 32 MB fp16 dt preact
    float4* summ  = (float4*)(ws + ((size_t)96 << 20));      //  8 MB chunk summaries
    float2* carry = (float2*)(ws + ((size_t)104 << 20));     //  4 MB chunk carries (ends 108 MB)

    cvt_all<<<(N4F + 3 * N4W) / 256, 256, 0, stream>>>(force, WA, WB, Wdt, Fb, Wcat);

    gemm_fused<<<dim3(128, 24), 256, 0, stream>>>(Fb, Wcat, bA, bB, bdt,
                                                  sA, sB, sDt);

    scan_pass1<<<BDIM * NCH, 256, 0, stream>>>(sA, sB, sDt, summ);
    scan_pass2<<<16, 256, 0, stream>>>(summ, carry);
    scan_pass3<<<BDIM * NCH, 256, 0, stream>>>(sA, sB, sDt, carry, vseq, xseq);
}

// Round 12
// 203.106 us; speedup vs baseline: 1.6557x; 1.0818x over previous
//
#include <hip/hip_runtime.h>
#include <hip/hip_bf16.h>
#include <math.h>

// ParallelMLayer: x_seq, v_seq = scan over A=sigmoid(F@WA.T+bA),
// dt=softplus(F@Wdt.T+bdt)*0.1*1.5^(d/128), B=(F@WB.T+bB)*dt
// v_t = A_t v_{t-1} + B_t ; x_t = x_{t-1} + dt_t * v_t
//
// R12: GEMM rebuilt as a faithful 8-phase counted-vmcnt template:
// 256x256 tile, BK=64, 8 waves (2x4), LDS 128 KB = 2par x 2half x [128][64]
// for A and B. Phase (mg,ng) = one C-quadrant x K=64 = 16 MFMA; stages 1
// half-tile of tile t+1 per phase (order A0,B0,B1,A1); end-of-phase
// vmcnt(4) + closing barrier (wait-then-barrier = cross-wave safe).
// Zero-conflict XOR swizzle (R5-verified). Scans unchanged from R11.

#define BDIM 4
#define LSEQ 4096
#define DDIM 1024
#define MROWS (BDIM*LSEQ)   // 16384
#define NCH 128             // scan chunks per sequence
#define CLEN (LSEQ/NCH)     // 32
#define N4W (DDIM*DDIM/4)   // 262144 (2^18)
#define N4F (MROWS*DDIM/4)  // 4194304

typedef __attribute__((ext_vector_type(8))) short s16x8;
typedef __attribute__((ext_vector_type(4))) float f32x4;

__device__ inline ushort f2bf(float f) {
    unsigned u = __builtin_bit_cast(unsigned, f);
    unsigned r = (u + 0x7fffu + ((u >> 16) & 1u)) >> 16;
    return (ushort)r;
}
__device__ inline ushort f2h(float f) {
    return __builtin_bit_cast(ushort, (_Float16)f);
}
__device__ inline float h2f(ushort u) {
    return (float)__builtin_bit_cast(_Float16, u);
}

__device__ inline void gld_lds16(const ushort* g, ushort* l) {
    __builtin_amdgcn_global_load_lds(
        (const __attribute__((address_space(1))) void*)g,
        (__attribute__((address_space(3))) void*)l, 16, 0, 0);
}

// ---- fused f32 -> bf16 conversion: force (N4F float4s) + WA/WB/Wdt ----
__global__ void cvt_all(const float* __restrict__ force, const float* __restrict__ wa,
                        const float* __restrict__ wb, const float* __restrict__ wdt,
                        ushort* __restrict__ Fb, ushort* __restrict__ Wcat) {
    int i = blockIdx.x * 256 + threadIdx.x;   // 0 .. N4F + 3*N4W - 1
    const float* s; ushort* dst; int j;
    if (i < N4F) {
        s = force; dst = Fb; j = i;
    } else {
        int k = i - N4F;                      // 0 .. 3*N4W-1
        int w = k >> 18;                      // N4W = 2^18
        j = k & (N4W - 1);
        s = (w == 0) ? wa : (w == 1) ? wb : wdt;
        dst = Wcat + (size_t)w * DDIM * DDIM;
    }
    float4 v = reinterpret_cast<const float4*>(s)[j];
    ushort4 o;
    o.x = f2bf(v.x); o.y = f2bf(v.y); o.z = f2bf(v.z); o.w = f2bf(v.w);
    reinterpret_cast<ushort4*>(dst)[j] = o;
}

// ---- 8-phase GEMM: S[i][j] = sum_k F[i][k]*Wcat[j][k] + bias[j] -> fp16 ----
// LDS ushort map: A(par,h) @ par*16384 + h*8192 ; B(par,h) @ 32768 + same.
// Half-tile = [128 rows][64 k-elems]; row r holds phys chunk p at global
// chunk p^(r&7)  (both-sides swizzle, conflict-free: R5-verified).

#define HBASE(HH) ((HH) < 2 ? (HH) * 8192 : 32768 + ((HH) - 2) * 8192)

#define VMW(n) asm volatile("s_waitcnt vmcnt(" #n ")" ::: "memory")
#define NOVM ((void)0)

// PAR,MG,NG,RDA,DOSTG,HH are literals. TK = staged tile index (runtime).
#define PHASE(PAR, MG, NG, RDA, DOSTG, HH, TK, VMSTMT)                               \
  {                                                                                  \
    if (RDA) {                                                                       \
      _Pragma("unroll")                                                              \
      for (int m = 0; m < 4; m++) {                                                  \
        afr[m][0] = *reinterpret_cast<const s16x8*>(                                 \
            &S[(PAR) * 16384 + (MG) * 8192 + rdA + m * 1024 + px0]);                 \
        afr[m][1] = *reinterpret_cast<const s16x8*>(                                 \
            &S[(PAR) * 16384 + (MG) * 8192 + rdA + m * 1024 + px1]);                 \
      }                                                                              \
    }                                                                                \
    _Pragma("unroll")                                                                \
    for (int j = 0; j < 2; j++) {                                                    \
      bfr[j][0] = *reinterpret_cast<const s16x8*>(                                   \
          &S[32768 + (PAR) * 16384 + (NG) * 8192 + rdB + j * 1024 + px0]);           \
      bfr[j][1] = *reinterpret_cast<const s16x8*>(                                   \
          &S[32768 + (PAR) * 16384 + (NG) * 8192 + rdB + j * 1024 + px1]);           \
    }                                                                                \
    if (DOSTG) {                                                                     \
      ushort* d0 = &S[HBASE(HH) + ((TK) & 1) * 16384 + wid * 512];                   \
      ushort* d1 = &S[HBASE(HH) + ((TK) & 1) * 16384 + 4096 + wid * 512];            \
      gld_lds16(gsrcs[HH][0] + (TK) * 64, d0);                                       \
      gld_lds16(gsrcs[HH][1] + (TK) * 64, d1);                                       \
    }                                                                                \
    asm volatile("" ::: "memory");                                                   \
    __builtin_amdgcn_s_barrier();                                                    \
    asm volatile("s_waitcnt lgkmcnt(0)" ::: "memory");                               \
    __builtin_amdgcn_sched_barrier(0);                                               \
    __builtin_amdgcn_s_setprio(1);                                                   \
    _Pragma("unroll")                                                                \
    for (int kk = 0; kk < 2; kk++)                                                   \
      _Pragma("unroll")                                                              \
      for (int m = 0; m < 4; m++)                                                    \
        _Pragma("unroll")                                                            \
        for (int j = 0; j < 2; j++)                                                  \
          acc[(MG) * 4 + m][(NG) * 2 + j] = __builtin_amdgcn_mfma_f32_16x16x32_bf16( \
              afr[m][kk], bfr[j][kk], acc[(MG) * 4 + m][(NG) * 2 + j], 0, 0, 0);     \
    __builtin_amdgcn_s_setprio(0);                                                   \
    VMSTMT;                                                                          \
    asm volatile("" ::: "memory");                                                   \
    __builtin_amdgcn_s_barrier();                                                    \
    asm volatile("" ::: "memory");                                                   \
  }

__global__ __launch_bounds__(512) void gemm_fused(
    const ushort* __restrict__ F, const ushort* __restrict__ Wc,
    const float* __restrict__ biasA, const float* __restrict__ biasB,
    const float* __restrict__ biasDt,
    ushort* __restrict__ sA, ushort* __restrict__ sB, ushort* __restrict__ sDt)
{
    __shared__ ushort S[65536];   // 128 KB
    const int t = threadIdx.x;
    // XCD-aware swizzle (768 % 8 == 0 -> bijective)
    const int swz = (blockIdx.x & 7) * 96 + (blockIdx.x >> 3);
    const int bi = swz / 12;     // 0..63  M tiles
    const int bj = swz % 12;     // 0..11  N tiles
    const int lane = t & 63, wid = t >> 6;
    const int wm = wid >> 2, wn = wid & 3;   // 2x4 waves
    const int lr = lane & 15, lg = lane >> 4;

    // staging sources: gload g covers rows g*64 + wid*8 + (lane>>3) of the
    // half-tile; phys chunk lane&7 holds global chunk (lane&7)^(R&7).
    const ushort* gsrcs[4][2];   // [HH][g]; HH: 0=A-h0 1=A-h1 2=B-h0 3=B-h1
#pragma unroll
    for (int h = 0; h < 2; h++)
#pragma unroll
        for (int g = 0; g < 2; g++) {
            const int R = g * 64 + wid * 8 + (lane >> 3);
            const int c8 = ((lane & 7) ^ (R & 7)) * 8;
            gsrcs[h][g]     = F  + ((size_t)(bi * 256 + h * 128 + R)) * DDIM + c8;
            gsrcs[2 + h][g] = Wc + ((size_t)(bj * 256 + h * 128 + R)) * DDIM + c8;
        }

    // read-side constants; rows-in-half: A: wm*64+m*16+lr, B: wn*32+j*16+lr
    const int rdA = (wm * 64 + lr) * 64;
    const int rdB = (wn * 32 + lr) * 64;
    const int px0 = ((0 * 4 + lg) ^ (lr & 7)) * 8;   // kk=0
    const int px1 = ((1 * 4 + lg) ^ (lr & 7)) * 8;   // kk=1

    f32x4 acc[8][4] = {};
    s16x8 afr[4][2], bfr[2][2];

    // prologue: stage tile 0 halves in consumption order A0,B0,B1,A1
    {
        ushort* d;
        const int HHo[4] = {0, 2, 3, 1};
#pragma unroll
        for (int s_ = 0; s_ < 4; s_++) {
            const int hh = HHo[s_];
            const int hb = (hh < 2) ? hh * 8192 : 32768 + (hh - 2) * 8192;
            d = &S[hb + wid * 512];
            gld_lds16(gsrcs[hh][0], d);
            d = &S[hb + 4096 + wid * 512];
            gld_lds16(gsrcs[hh][1], d);
        }
    }
    VMW(4);
    asm volatile("" ::: "memory");
    __builtin_amdgcn_s_barrier();
    asm volatile("" ::: "memory");

    // main loop: 7 uniform iterations (tiles t0=2i par0, t1=2i+1 par1;
    // stage t1 @P1-P4, t2=2i+2 @P5-P8)
    for (int it = 0; it < 7; ++it) {
        const int t1 = 2 * it + 1;
        const int t2 = 2 * it + 2;
        PHASE(0, 0, 0, 1, 1, 0, t1, VMW(4))   // P1: A0(t1)
        PHASE(0, 0, 1, 0, 1, 2, t1, VMW(4))   // P2: B0(t1)
        PHASE(0, 1, 0, 1, 1, 3, t1, NOVM)     // P3: B1(t1)
        PHASE(0, 1, 1, 0, 1, 1, t1, VMW(4))   // P4: A1(t1)
        PHASE(1, 0, 0, 1, 1, 0, t2, VMW(4))   // P5: A0(t2)
        PHASE(1, 0, 1, 0, 1, 2, t2, VMW(4))   // P6: B0(t2)
        PHASE(1, 1, 0, 1, 1, 3, t2, NOVM)     // P7: B1(t2)
        PHASE(1, 1, 1, 0, 1, 1, t2, VMW(4))   // P8: A1(t2)
    }
    // peeled last iteration (t0=14, t1=15; no t2 stages; drain waits)
    PHASE(0, 0, 0, 1, 1, 0, 15, VMW(4))
    PHASE(0, 0, 1, 0, 1, 2, 15, VMW(4))
    PHASE(0, 1, 0, 1, 1, 3, 15, NOVM)
    PHASE(0, 1, 1, 0, 1, 1, 15, VMW(4))
    PHASE(1, 0, 0, 1, 0, 0, 0,  VMW(2))
    PHASE(1, 0, 1, 0, 0, 0, 0,  VMW(0))
    PHASE(1, 1, 0, 1, 0, 0, 0,  NOVM)
    PHASE(1, 1, 1, 0, 0, 0, 0,  NOVM)

    // epilogue: bias-add + fp16 store. C/D: col=lane&15, row=(lane>>4)*4+reg
    // row = bi*256 + mg*128 + wm*64 + m*16 + lg*4 + r
    // col = bj*256 + ng*128 + wn*32 + j*16 + lr
    const int mat = bj >> 2;                     // 0:A 1:B 2:dt
    const float* bias = (mat == 0) ? biasA : (mat == 1) ? biasB : biasDt;
    ushort* outp = (mat == 0) ? sA : (mat == 1) ? sB : sDt;

#pragma unroll
    for (int ngj = 0; ngj < 4; ngj++) {
        const int ng = ngj >> 1, j = ngj & 1;
        const int d = (bj & 3) * 256 + ng * 128 + wn * 32 + j * 16 + lr;
        const float bb = bias[d];
#pragma unroll
        for (int mgm = 0; mgm < 8; mgm++) {
            const int mg = mgm >> 2, m = mgm & 3;
#pragma unroll
            for (int r = 0; r < 4; r++) {
                const size_t row = (size_t)bi * 256 + mg * 128 + wm * 64 + m * 16 + lg * 4 + r;
                outp[row * DDIM + d] = f2h(acc[mgm][ngj][r] + bb);
            }
        }
    }
}

// activation helpers (scan-side) — HW transcendentals only (R11-verified)
__device__ inline float sigm(float s) {
    return __builtin_amdgcn_rcpf(1.0f + __expf(-s));
}
__device__ inline float softp(float s) {
    return fmaxf(s, 0.0f) + __logf(1.0f + __expf(-fabsf(s)));
}

// ---- scan pass 1: per (b, chunk, d) composite map (a, c, bv, bx) ----
__global__ void scan_pass1(const ushort* __restrict__ sA, const ushort* __restrict__ sB,
                           const ushort* __restrict__ sDt, float4* __restrict__ summ)
{
    const int c = blockIdx.x & (NCH - 1);
    const int b = blockIdx.x >> 7;       // NCH = 128
    const int d4 = threadIdx.x;          // 0..255, covers d = 4*d4..+3
    size_t idx4 = ((size_t)b * LSEQ + (size_t)c * CLEN) * (DDIM / 4) + d4;
    const float scl = 0.1f * exp2f(0.58496250072f * (float)(d4 >> 5)); // 0.1*1.5^(d>>7)
    float a[4] = {1.f,1.f,1.f,1.f}, cc[4] = {}, bv[4] = {}, bx[4] = {};
    for (int i = 0; i < CLEN; i++) {
        ushort4 ua = reinterpret_cast<const ushort4*>(sA)[idx4];
        ushort4 ub = reinterpret_cast<const ushort4*>(sB)[idx4];
        ushort4 ud = reinterpret_cast<const ushort4*>(sDt)[idx4];
        const ushort va[4] = {ua.x, ua.y, ua.z, ua.w};
        const ushort vb[4] = {ub.x, ub.y, ub.z, ub.w};
        const ushort vd[4] = {ud.x, ud.y, ud.z, ud.w};
#pragma unroll
        for (int j = 0; j < 4; j++) {
            const float A  = sigm(h2f(va[j]));
            const float dt = softp(h2f(vd[j])) * scl;
            const float bval = h2f(vb[j]) * dt;
            a[j] *= A;
            cc[j] = fmaf(dt, a[j], cc[j]);
            bv[j] = fmaf(A, bv[j], bval);
            bx[j] = fmaf(dt, bv[j], bx[j]);
        }
        idx4 += DDIM / 4;
    }
    const size_t base = ((size_t)b * NCH + c) * DDIM + (size_t)d4 * 4;
#pragma unroll
    for (int j = 0; j < 4; j++)
        summ[base + j] = make_float4(a[j], cc[j], bv[j], bx[j]);
}

// ---- scan pass 2: serial over chunks per channel -> carry-in (v, x) ----
__global__ void scan_pass2(const float4* __restrict__ summ, float2* __restrict__ carry)
{
    const int idx = blockIdx.x * 256 + threadIdx.x;   // 4096 channels
    const int b = idx >> 10, d = idx & 1023;
    float v = 0.0f, x = 0.0f;
    for (int c = 0; c < NCH; c++) {
        const size_t o = ((size_t)b * NCH + c) * DDIM + d;
        carry[o] = make_float2(v, x);
        float4 s = summ[o];
        x = x + s.y * v + s.w;   // x' = x + c*v + bx (uses OLD v)
        v = s.x * v + s.z;       // v' = a*v + bv
    }
}

// ---- scan pass 3: finalize with carry; write v_seq/x_seq fp32 ----
__global__ void scan_pass3(const ushort* __restrict__ sA, const ushort* __restrict__ sB,
                           const ushort* __restrict__ sDt, const float2* __restrict__ carry,
                           float* __restrict__ VS, float* __restrict__ XS)
{
    const int c = blockIdx.x & (NCH - 1);
    const int b = blockIdx.x >> 7;
    const int d4 = threadIdx.x;
    size_t idx4 = ((size_t)b * LSEQ + (size_t)c * CLEN) * (DDIM / 4) + d4;
    const float scl = 0.1f * exp2f(0.58496250072f * (float)(d4 >> 5));
    const size_t cbase = ((size_t)b * NCH + c) * DDIM + (size_t)d4 * 4;
    f32x4 v, x;
#pragma unroll
    for (int j = 0; j < 4; j++) {
        float2 cr = carry[cbase + j];
        v[j] = cr.x; x[j] = cr.y;
    }
    f32x4* VS4 = (f32x4*)VS;
    f32x4* XS4 = (f32x4*)XS;
    for (int i = 0; i < CLEN; i++) {
        ushort4 ua = reinterpret_cast<const ushort4*>(sA)[idx4];
        ushort4 ub = reinterpret_cast<const ushort4*>(sB)[idx4];
        ushort4 ud = reinterpret_cast<const ushort4*>(sDt)[idx4];
        const ushort va[4] = {ua.x, ua.y, ua.z, ua.w};
        const ushort vb[4] = {ub.x, ub.y, ub.z, ub.w};
        const ushort vd[4] = {ud.x, ud.y, ud.z, ud.w};
#pragma unroll
        for (int j = 0; j < 4; j++) {
            const float A  = sigm(h2f(va[j]));
            const float dt = softp(h2f(vd[j])) * scl;
            v[j] = fmaf(A, v[j], h2f(vb[j]) * dt);
            x[j] = fmaf(dt, v[j], x[j]);
        }
        VS4[idx4] = v;
        XS4[idx4] = x;
        idx4 += DDIM / 4;
    }
}

extern "C" void kernel_launch(void* const* d_in, const int* in_sizes, int n_in,
                              void* d_out, int out_size, void* d_ws, size_t ws_size,
                              hipStream_t stream) {
    const float* force = (const float*)d_in[2];
    const float* WA  = (const float*)d_in[5];
    const float* bA  = (const float*)d_in[6];
    const float* WB  = (const float*)d_in[7];
    const float* bB  = (const float*)d_in[8];
    const float* Wdt = (const float*)d_in[9];
    const float* bdt = (const float*)d_in[10];

    float* xseq = (float*)d_out;                          // [B,L,D] first output
    float* vseq = xseq + (size_t)MROWS * DDIM;            // [B,L,D] second output

    // bf16 staging buffers live in d_out (dead before pass3 writes there):
    ushort* Fb   = (ushort*)xseq;   // 32 MB bf16 force in x region
    ushort* Wcat = (ushort*)vseq;   //  6 MB bf16 [WA;WB;Wdt] in v region

    char* ws = (char*)d_ws;
    ushort* sA    = (ushort*) ws;                            // 32 MB fp16 A preact
    ushort* sB    = (ushort*)(ws + ((size_t)32 << 20));      // 32 MB fp16 B preact
    ushort* sDt   = (ushort*)(ws + ((size_t)64 << 20));      // 32 MB fp16 dt preact
    float4* summ  = (float4*)(ws + ((size_t)96 << 20));      //  8 MB chunk summaries
    float2* carry = (float2*)(ws + ((size_t)104 << 20));     //  4 MB chunk carries (ends 108 MB)

    cvt_all<<<(N4F + 3 * N4W) / 256, 256, 0, stream>>>(force, WA, WB, Wdt, Fb, Wcat);

    gemm_fused<<<768, 512, 0, stream>>>(Fb, Wcat, bA, bB, bdt, sA, sB, sDt);

    scan_pass1<<<BDIM * NCH, 256, 0, stream>>>(sA, sB, sDt, summ);
    scan_pass2<<<16, 256, 0, stream>>>(summ, carry);
    scan_pass3<<<BDIM * NCH, 256, 0, stream>>>(sA, sB, sDt, carry, vseq, xseq);
}

// Round 15
// 202.544 us; speedup vs baseline: 1.6603x; 1.0028x over previous
//
#include <hip/hip_runtime.h>
#include <hip/hip_bf16.h>
#include <math.h>

// ParallelMLayer: x_seq, v_seq = scan over A=sigmoid(F@WA.T+bA),
// dt=softplus(F@Wdt.T+bdt)*0.1*1.5^(d/128), B=(F@WB.T+bB)*dt
// v_t = A_t v_{t-1} + B_t ; x_t = x_{t-1} + dt_t * v_t
//
// R13: R12's 8-phase GEMM with formula-correct counted waits: uniform
// vmcnt(6) (= 2 loads/half-tile x 3 half-tiles in flight) instead of the
// over-draining vmcnt(4); epilogue drains 6->4->2->0. Coverage invariant
// re-derived: each region's reader is preceded by a per-wave wait retiring
// the stager's own loads + a publishing barrier. Scans unchanged.

#define BDIM 4
#define LSEQ 4096
#define DDIM 1024
#define MROWS (BDIM*LSEQ)   // 16384
#define NCH 128             // scan chunks per sequence
#define CLEN (LSEQ/NCH)     // 32
#define N4W (DDIM*DDIM/4)   // 262144 (2^18)
#define N4F (MROWS*DDIM/4)  // 4194304

typedef __attribute__((ext_vector_type(8))) short s16x8;
typedef __attribute__((ext_vector_type(4))) float f32x4;

__device__ inline ushort f2bf(float f) {
    unsigned u = __builtin_bit_cast(unsigned, f);
    unsigned r = (u + 0x7fffu + ((u >> 16) & 1u)) >> 16;
    return (ushort)r;
}
__device__ inline ushort f2h(float f) {
    return __builtin_bit_cast(ushort, (_Float16)f);
}
__device__ inline float h2f(ushort u) {
    return (float)__builtin_bit_cast(_Float16, u);
}

__device__ inline void gld_lds16(const ushort* g, ushort* l) {
    __builtin_amdgcn_global_load_lds(
        (const __attribute__((address_space(1))) void*)g,
        (__attribute__((address_space(3))) void*)l, 16, 0, 0);
}

// ---- fused f32 -> bf16 conversion: force (N4F float4s) + WA/WB/Wdt ----
__global__ void cvt_all(const float* __restrict__ force, const float* __restrict__ wa,
                        const float* __restrict__ wb, const float* __restrict__ wdt,
                        ushort* __restrict__ Fb, ushort* __restrict__ Wcat) {
    int i = blockIdx.x * 256 + threadIdx.x;   // 0 .. N4F + 3*N4W - 1
    const float* s; ushort* dst; int j;
    if (i < N4F) {
        s = force; dst = Fb; j = i;
    } else {
        int k = i - N4F;                      // 0 .. 3*N4W-1
        int w = k >> 18;                      // N4W = 2^18
        j = k & (N4W - 1);
        s = (w == 0) ? wa : (w == 1) ? wb : wdt;
        dst = Wcat + (size_t)w * DDIM * DDIM;
    }
    float4 v = reinterpret_cast<const float4*>(s)[j];
    ushort4 o;
    o.x = f2bf(v.x); o.y = f2bf(v.y); o.z = f2bf(v.z); o.w = f2bf(v.w);
    reinterpret_cast<ushort4*>(dst)[j] = o;
}

// ---- 8-phase GEMM: S[i][j] = sum_k F[i][k]*Wcat[j][k] + bias[j] -> fp16 ----
// LDS ushort map: A(par,h) @ par*16384 + h*8192 ; B(par,h) @ 32768 + same.
// Half-tile = [128 rows][64 k-elems]; row r holds phys chunk p at global
// chunk p^(r&7)  (both-sides swizzle, conflict-free: R5-verified).

#define HBASE(HH) ((HH) < 2 ? (HH) * 8192 : 32768 + ((HH) - 2) * 8192)

#define VMW(n) asm volatile("s_waitcnt vmcnt(" #n ")" ::: "memory")
#define NOVM ((void)0)

// PAR,MG,NG,RDA,DOSTG,HH are literals. TK = staged tile index (runtime).
#define PHASE(PAR, MG, NG, RDA, DOSTG, HH, TK, VMSTMT)                               \
  {                                                                                  \
    if (RDA) {                                                                       \
      _Pragma("unroll")                                                              \
      for (int m = 0; m < 4; m++) {                                                  \
        afr[m][0] = *reinterpret_cast<const s16x8*>(                                 \
            &S[(PAR) * 16384 + (MG) * 8192 + rdA + m * 1024 + px0]);                 \
        afr[m][1] = *reinterpret_cast<const s16x8*>(                                 \
            &S[(PAR) * 16384 + (MG) * 8192 + rdA + m * 1024 + px1]);                 \
      }                                                                              \
    }                                                                                \
    _Pragma("unroll")                                                                \
    for (int j = 0; j < 2; j++) {                                                    \
      bfr[j][0] = *reinterpret_cast<const s16x8*>(                                   \
          &S[32768 + (PAR) * 16384 + (NG) * 8192 + rdB + j * 1024 + px0]);           \
      bfr[j][1] = *reinterpret_cast<const s16x8*>(                                   \
          &S[32768 + (PAR) * 16384 + (NG) * 8192 + rdB + j * 1024 + px1]);           \
    }                                                                                \
    if (DOSTG) {                                                                     \
      ushort* d0 = &S[HBASE(HH) + ((TK) & 1) * 16384 + wid * 512];                   \
      ushort* d1 = &S[HBASE(HH) + ((TK) & 1) * 16384 + 4096 + wid * 512];            \
      gld_lds16(gsrcs[HH][0] + (TK) * 64, d0);                                       \
      gld_lds16(gsrcs[HH][1] + (TK) * 64, d1);                                       \
    }                                                                                \
    asm volatile("" ::: "memory");                                                   \
    __builtin_amdgcn_s_barrier();                                                    \
    asm volatile("s_waitcnt lgkmcnt(0)" ::: "memory");                               \
    __builtin_amdgcn_sched_barrier(0);                                               \
    __builtin_amdgcn_s_setprio(1);                                                   \
    _Pragma("unroll")                                                                \
    for (int kk = 0; kk < 2; kk++)                                                   \
      _Pragma("unroll")                                                              \
      for (int m = 0; m < 4; m++)                                                    \
        _Pragma("unroll")                                                            \
        for (int j = 0; j < 2; j++)                                                  \
          acc[(MG) * 4 + m][(NG) * 2 + j] = __builtin_amdgcn_mfma_f32_16x16x32_bf16( \
              afr[m][kk], bfr[j][kk], acc[(MG) * 4 + m][(NG) * 2 + j], 0, 0, 0);     \
    __builtin_amdgcn_s_setprio(0);                                                   \
    VMSTMT;                                                                          \
    asm volatile("" ::: "memory");                                                   \
    __builtin_amdgcn_s_barrier();                                                    \
    asm volatile("" ::: "memory");                                                   \
  }

__global__ __launch_bounds__(512) void gemm_fused(
    const ushort* __restrict__ F, const ushort* __restrict__ Wc,
    const float* __restrict__ biasA, const float* __restrict__ biasB,
    const float* __restrict__ biasDt,
    ushort* __restrict__ sA, ushort* __restrict__ sB, ushort* __restrict__ sDt)
{
    __shared__ ushort S[65536];   // 128 KB
    const int t = threadIdx.x;
    // XCD-aware swizzle (768 % 8 == 0 -> bijective)
    const int swz = (blockIdx.x & 7) * 96 + (blockIdx.x >> 3);
    const int bi = swz / 12;     // 0..63  M tiles
    const int bj = swz % 12;     // 0..11  N tiles
    const int lane = t & 63, wid = t >> 6;
    const int wm = wid >> 2, wn = wid & 3;   // 2x4 waves
    const int lr = lane & 15, lg = lane >> 4;

    // staging sources: gload g covers rows g*64 + wid*8 + (lane>>3) of the
    // half-tile; phys chunk lane&7 holds global chunk (lane&7)^(R&7).
    const ushort* gsrcs[4][2];   // [HH][g]; HH: 0=A-h0 1=A-h1 2=B-h0 3=B-h1
#pragma unroll
    for (int h = 0; h < 2; h++)
#pragma unroll
        for (int g = 0; g < 2; g++) {
            const int R = g * 64 + wid * 8 + (lane >> 3);
            const int c8 = ((lane & 7) ^ (R & 7)) * 8;
            gsrcs[h][g]     = F  + ((size_t)(bi * 256 + h * 128 + R)) * DDIM + c8;
            gsrcs[2 + h][g] = Wc + ((size_t)(bj * 256 + h * 128 + R)) * DDIM + c8;
        }

    // read-side constants; rows-in-half: A: wm*64+m*16+lr, B: wn*32+j*16+lr
    const int rdA = (wm * 64 + lr) * 64;
    const int rdB = (wn * 32 + lr) * 64;
    const int px0 = ((0 * 4 + lg) ^ (lr & 7)) * 8;   // kk=0
    const int px1 = ((1 * 4 + lg) ^ (lr & 7)) * 8;   // kk=1

    f32x4 acc[8][4] = {};
    s16x8 afr[4][2], bfr[2][2];

    // prologue: stage tile 0 halves in consumption order A0,B0,B1,A1
    {
        ushort* d;
        const int HHo[4] = {0, 2, 3, 1};
#pragma unroll
        for (int s_ = 0; s_ < 4; s_++) {
            const int hh = HHo[s_];
            const int hb = (hh < 2) ? hh * 8192 : 32768 + (hh - 2) * 8192;
            d = &S[hb + wid * 512];
            gld_lds16(gsrcs[hh][0], d);
            d = &S[hb + 4096 + wid * 512];
            gld_lds16(gsrcs[hh][1], d);
        }
    }
    VMW(6);
    asm volatile("" ::: "memory");
    __builtin_amdgcn_s_barrier();
    asm volatile("" ::: "memory");

    // main loop: 7 uniform iterations (tiles t0=2i par0, t1=2i+1 par1;
    // stage t1 @P1-P4, t2=2i+2 @P5-P8). Uniform vmcnt(6): each phase-end
    // retires exactly the pair the phase 4-ahead will read; 6 stay in flight.
    for (int it = 0; it < 7; ++it) {
        const int t1 = 2 * it + 1;
        const int t2 = 2 * it + 2;
        PHASE(0, 0, 0, 1, 1, 0, t1, VMW(6))   // P1: stage A0(t1)
        PHASE(0, 0, 1, 0, 1, 2, t1, VMW(6))   // P2: stage B0(t1)
        PHASE(0, 1, 0, 1, 1, 3, t1, VMW(6))   // P3: stage B1(t1)
        PHASE(0, 1, 1, 0, 1, 1, t1, VMW(6))   // P4: stage A1(t1)
        PHASE(1, 0, 0, 1, 1, 0, t2, VMW(6))   // P5: stage A0(t2)
        PHASE(1, 0, 1, 0, 1, 2, t2, VMW(6))   // P6: stage B0(t2)
        PHASE(1, 1, 0, 1, 1, 3, t2, VMW(6))   // P7: stage B1(t2)
        PHASE(1, 1, 1, 0, 1, 1, t2, VMW(6))   // P8: stage A1(t2)
    }
    // peeled last iteration (t0=14, t1=15; no t2 stages; drain 6->4->2->0)
    PHASE(0, 0, 0, 1, 1, 0, 15, VMW(6))
    PHASE(0, 0, 1, 0, 1, 2, 15, VMW(6))
    PHASE(0, 1, 0, 1, 1, 3, 15, VMW(6))
    PHASE(0, 1, 1, 0, 1, 1, 15, VMW(6))
    PHASE(1, 0, 0, 1, 0, 0, 0,  VMW(4))
    PHASE(1, 0, 1, 0, 0, 0, 0,  VMW(2))
    PHASE(1, 1, 0, 1, 0, 0, 0,  VMW(0))
    PHASE(1, 1, 1, 0, 0, 0, 0,  NOVM)

    // epilogue: bias-add + fp16 store. C/D: col=lane&15, row=(lane>>4)*4+reg
    const int mat = bj >> 2;                     // 0:A 1:B 2:dt
    const float* bias = (mat == 0) ? biasA : (mat == 1) ? biasB : biasDt;
    ushort* outp = (mat == 0) ? sA : (mat == 1) ? sB : sDt;

#pragma unroll
    for (int ngj = 0; ngj < 4; ngj++) {
        const int ng = ngj >> 1, j = ngj & 1;
        const int d = (bj & 3) * 256 + ng * 128 + wn * 32 + j * 16 + lr;
        const float bb = bias[d];
#pragma unroll
        for (int mgm = 0; mgm < 8; mgm++) {
            const int mg = mgm >> 2, m = mgm & 3;
#pragma unroll
            for (int r = 0; r < 4; r++) {
                const size_t row = (size_t)bi * 256 + mg * 128 + wm * 64 + m * 16 + lg * 4 + r;
                outp[row * DDIM + d] = f2h(acc[mgm][ngj][r] + bb);
            }
        }
    }
}

// activation helpers (scan-side) — HW transcendentals only (R11-verified)
__device__ inline float sigm(float s) {
    return __builtin_amdgcn_rcpf(1.0f + __expf(-s));
}
__device__ inline float softp(float s) {
    return fmaxf(s, 0.0f) + __logf(1.0f + __expf(-fabsf(s)));
}

// ---- scan pass 1: per (b, chunk, d) composite map (a, c, bv, bx) ----
__global__ void scan_pass1(const ushort* __restrict__ sA, const ushort* __restrict__ sB,
                           const ushort* __restrict__ sDt, float4* __restrict__ summ)
{
    const int c = blockIdx.x & (NCH - 1);
    const int b = blockIdx.x >> 7;       // NCH = 128
    const int d4 = threadIdx.x;          // 0..255, covers d = 4*d4..+3
    size_t idx4 = ((size_t)b * LSEQ + (size_t)c * CLEN) * (DDIM / 4) + d4;
    const float scl = 0.1f * exp2f(0.58496250072f * (float)(d4 >> 5)); // 0.1*1.5^(d>>7)
    float a[4] = {1.f,1.f,1.f,1.f}, cc[4] = {}, bv[4] = {}, bx[4] = {};
    for (int i = 0; i < CLEN; i++) {
        ushort4 ua = reinterpret_cast<const ushort4*>(sA)[idx4];
        ushort4 ub = reinterpret_cast<const ushort4*>(sB)[idx4];
        ushort4 ud = reinterpret_cast<const ushort4*>(sDt)[idx4];
        const ushort va[4] = {ua.x, ua.y, ua.z, ua.w};
        const ushort vb[4] = {ub.x, ub.y, ub.z, ub.w};
        const ushort vd[4] = {ud.x, ud.y, ud.z, ud.w};
#pragma unroll
        for (int j = 0; j < 4; j++) {
            const float A  = sigm(h2f(va[j]));
            const float dt = softp(h2f(vd[j])) * scl;
            const float bval = h2f(vb[j]) * dt;
            a[j] *= A;
            cc[j] = fmaf(dt, a[j], cc[j]);
            bv[j] = fmaf(A, bv[j], bval);
            bx[j] = fmaf(dt, bv[j], bx[j]);
        }
        idx4 += DDIM / 4;
    }
    const size_t base = ((size_t)b * NCH + c) * DDIM + (size_t)d4 * 4;
#pragma unroll
    for (int j = 0; j < 4; j++)
        summ[base + j] = make_float4(a[j], cc[j], bv[j], bx[j]);
}

// ---- scan pass 2: serial over chunks per channel -> carry-in (v, x) ----
__global__ void scan_pass2(const float4* __restrict__ summ, float2* __restrict__ carry)
{
    const int idx = blockIdx.x * 256 + threadIdx.x;   // 4096 channels
    const int b = idx >> 10, d = idx & 1023;
    float v = 0.0f, x = 0.0f;
    for (int c = 0; c < NCH; c++) {
        const size_t o = ((size_t)b * NCH + c) * DDIM + d;
        carry[o] = make_float2(v, x);
        float4 s = summ[o];
        x = x + s.y * v + s.w;   // x' = x + c*v + bx (uses OLD v)
        v = s.x * v + s.z;       // v' = a*v + bv
    }
}

// ---- scan pass 3: finalize with carry; write v_seq/x_seq fp32 ----
__global__ void scan_pass3(const ushort* __restrict__ sA, const ushort* __restrict__ sB,
                           const ushort* __restrict__ sDt, const float2* __restrict__ carry,
                           float* __restrict__ VS, float* __restrict__ XS)
{
    const int c = blockIdx.x & (NCH - 1);
    const int b = blockIdx.x >> 7;
    const int d4 = threadIdx.x;
    size_t idx4 = ((size_t)b * LSEQ + (size_t)c * CLEN) * (DDIM / 4) + d4;
    const float scl = 0.1f * exp2f(0.58496250072f * (float)(d4 >> 5));
    const size_t cbase = ((size_t)b * NCH + c) * DDIM + (size_t)d4 * 4;
    f32x4 v, x;
#pragma unroll
    for (int j = 0; j < 4; j++) {
        float2 cr = carry[cbase + j];
        v[j] = cr.x; x[j] = cr.y;
    }
    f32x4* VS4 = (f32x4*)VS;
    f32x4* XS4 = (f32x4*)XS;
    for (int i = 0; i < CLEN; i++) {
        ushort4 ua = reinterpret_cast<const ushort4*>(sA)[idx4];
        ushort4 ub = reinterpret_cast<const ushort4*>(sB)[idx4];
        ushort4 ud = reinterpret_cast<const ushort4*>(sDt)[idx4];
        const ushort va[4] = {ua.x, ua.y, ua.z, ua.w};
        const ushort vb[4] = {ub.x, ub.y, ub.z, ub.w};
        const ushort vd[4] = {ud.x, ud.y, ud.z, ud.w};
#pragma unroll
        for (int j = 0; j < 4; j++) {
            const float A  = sigm(h2f(va[j]));
            const float dt = softp(h2f(vd[j])) * scl;
            v[j] = fmaf(A, v[j], h2f(vb[j]) * dt);
            x[j] = fmaf(dt, v[j], x[j]);
        }
        VS4[idx4] = v;
        XS4[idx4] = x;
        idx4 += DDIM / 4;
    }
}

extern "C" void kernel_launch(void* const* d_in, const int* in_sizes, int n_in,
                              void* d_out, int out_size, void* d_ws, size_t ws_size,
                              hipStream_t stream) {
    const float* force = (const float*)d_in[2];
    const float* WA  = (const float*)d_in[5];
    const float* bA  = (const float*)d_in[6];
    const float* WB  = (const float*)d_in[7];
    const float* bB  = (const float*)d_in[8];
    const float* Wdt = (const float*)d_in[9];
    const float* bdt = (const float*)d_in[10];

    float* xseq = (float*)d_out;                          // [B,L,D] first output
    float* vseq = xseq + (size_t)MROWS * DDIM;            // [B,L,D] second output

    // bf16 staging buffers live in d_out (dead before pass3 writes there):
    ushort* Fb   = (ushort*)xseq;   // 32 MB bf16 force in x region
    ushort* Wcat = (ushort*)vseq;   //  6 MB bf16 [WA;WB;Wdt] in v region

    char* ws = (char*)d_ws;
    ushort* sA    = (ushort*) ws;                            // 32 MB fp16 A preact
    ushort* sB    = (ushort*)(ws + ((size_t)32 << 20));      // 32 MB fp16 B preact
    ushort* sDt   = (ushort*)(ws + ((size_t)64 << 20));      // 32 MB fp16 dt preact
    float4* summ  = (float4*)(ws + ((size_t)96 << 20));      //  8 MB chunk summaries
    float2* carry = (float2*)(ws + ((size_t)104 << 20));     //  4 MB chunk carries (ends 108 MB)

    cvt_all<<<(N4F + 3 * N4W) / 256, 256, 0, stream>>>(force, WA, WB, Wdt, Fb, Wcat);

    gemm_fused<<<768, 512, 0, stream>>>(Fb, Wcat, bA, bB, bdt, sA, sB, sDt);

    scan_pass1<<<BDIM * NCH, 256, 0, stream>>>(sA, sB, sDt, summ);
    scan_pass2<<<16, 256, 0, stream>>>(summ, carry);
    scan_pass3<<<BDIM * NCH, 256, 0, stream>>>(sA, sB, sDt, carry, vseq, xseq);
}